// Round 3
// baseline (69626.465 us; speedup 1.0000x reference)
//
#include <hip/hip_runtime.h>
#include <math.h>

#define NB 256
#define NS 128
#define NCOL 64
#define NT 60
#define DENC 512
#define DRNN 512
#define DATT 512
#define DACT 128
#define DTYP 64
#define DG 2048
#define NEGV (-1e9f)
#define NBLK 256
#define NBH 131072   // NB*DRNN

typedef unsigned short ushort_t;
typedef __attribute__((ext_vector_type(8))) short short8;
typedef __attribute__((ext_vector_type(4))) float f32x4;

__device__ __forceinline__ float sigf(float x) { return 1.0f / (1.0f + __expf(-x)); }
__device__ __forceinline__ float tanhfast(float x) {
  x = fminf(fmaxf(x, -15.0f), 15.0f);
  float e = __expf(-2.0f * x);
  return (1.0f - e) / (1.0f + e);
}

__device__ __forceinline__ ushort_t f2bf(float f) {
  union { float f; unsigned u; } v; v.f = f;
  unsigned r = v.u + 0x7fffu + ((v.u >> 16) & 1u);
  return (ushort_t)(r >> 16);
}
__device__ __forceinline__ float bf2f(ushort_t b) {
  union { unsigned u; float f; } v; v.u = ((unsigned)b) << 16; return v.f;
}
__device__ __forceinline__ void ld8(const float* p, float* d) {
  f32x4 x = *(const f32x4*)p, y = *(const f32x4*)(p + 4);
  d[0]=x[0]; d[1]=x[1]; d[2]=x[2]; d[3]=x[3];
  d[4]=y[0]; d[5]=y[1]; d[6]=y[2]; d[7]=y[3];
}
__device__ __forceinline__ short8 cvt8(const float* p) {
  f32x4 x = *(const f32x4*)p, y = *(const f32x4*)(p + 4);
  short8 r;
  r[0]=(short)f2bf(x[0]); r[1]=(short)f2bf(x[1]); r[2]=(short)f2bf(x[2]); r[3]=(short)f2bf(x[3]);
  r[4]=(short)f2bf(y[0]); r[5]=(short)f2bf(y[1]); r[6]=(short)f2bf(y[2]); r[7]=(short)f2bf(y[3]);
  return r;
}

// ---------------- grid barrier (device-scope, sense via generation) --------
__device__ __forceinline__ void gbar(unsigned* bar) {
  __syncthreads();
  if (threadIdx.x == 0) {
    __threadfence();
    unsigned g = __hip_atomic_load(&bar[1], __ATOMIC_RELAXED, __HIP_MEMORY_SCOPE_AGENT);
    unsigned v = __hip_atomic_fetch_add(&bar[0], 1u, __ATOMIC_ACQ_REL, __HIP_MEMORY_SCOPE_AGENT);
    if (v == NBLK - 1u) {
      __hip_atomic_store(&bar[0], 0u, __ATOMIC_RELAXED, __HIP_MEMORY_SCOPE_AGENT);
      __hip_atomic_fetch_add(&bar[1], 1u, __ATOMIC_RELEASE, __HIP_MEMORY_SCOPE_AGENT);
    } else {
      while (__hip_atomic_load(&bar[1], __ATOMIC_ACQUIRE, __HIP_MEMORY_SCOPE_AGENT) == g)
        __builtin_amdgcn_s_sleep(2);
    }
  }
  __syncthreads();
}

// -------------------------------------------------------------------------
__global__ __launch_bounds__(256) void zero_kernel(float* __restrict__ p, int n) {
  int i = blockIdx.x * 256 + threadIdx.x;
  if (i < n) p[i] = 0.0f;
}

// pack f32 weight into bf16 [(K/8)][Ntot][8]
__global__ __launch_bounds__(256) void pack_w(const float* __restrict__ src,
    ushort_t* __restrict__ dst, int Ksub, int Nsub, int Ntot, int K0, int N0, int ldsrc)
{
  int idx = blockIdx.x * 256 + threadIdx.x;
  if (idx >= Ksub * Nsub) return;
  int k = idx / Nsub, n = idx - k * Nsub;
  int gk = K0 + k;
  dst[((size_t)(gk >> 3) * Ntot + (N0 + n)) * 8 + (gk & 7)] =
      f2bf(src[(size_t)k * ldsrc + n]);
}

// standalone MFMA GEMM used once for colin (A f32)
__global__ __launch_bounds__(256) void gemm_bf16(
    const float* __restrict__ A1, int lda1,
    const ushort_t* __restrict__ Bp, ushort_t* __restrict__ Cb, int ldc,
    int N, int K)
{
  __shared__ short As[2][4096];
  __shared__ short Bs[2][4096];
  const int tid = threadIdx.x;
  const int lane = tid & 63, w = tid >> 6;
  const int wr = w >> 1, wc = w & 1;
  const int mBase = blockIdx.y * 64, nBase = blockIdx.x * 64;
  const int nt = K >> 6;
  f32x4 ra0[2], ra1[2];
  short8 rb[2];
  auto issue = [&](int kt) {
    #pragma unroll
    for (int s = 0; s < 2; ++s) {
      int slot = tid + s * 256;
      int kc = slot >> 6, m = slot & 63;
      int k0 = (kt << 6) + kc * 8;
      const float* p = A1 + (size_t)(mBase + m) * lda1 + k0;
      ra0[s] = *(const f32x4*)p;
      ra1[s] = *(const f32x4*)(p + 4);
      rb[s] = *(const short8*)(Bp + ((size_t)(k0 >> 3) * N + nBase + m) * 8);
    }
  };
  auto store = [&](int buf) {
    #pragma unroll
    for (int s = 0; s < 2; ++s) {
      int slot = tid + s * 256;
      short8 av;
      av[0]=(short)f2bf(ra0[s][0]); av[1]=(short)f2bf(ra0[s][1]);
      av[2]=(short)f2bf(ra0[s][2]); av[3]=(short)f2bf(ra0[s][3]);
      av[4]=(short)f2bf(ra1[s][0]); av[5]=(short)f2bf(ra1[s][1]);
      av[6]=(short)f2bf(ra1[s][2]); av[7]=(short)f2bf(ra1[s][3]);
      *(short8*)&As[buf][slot * 8] = av;
      *(short8*)&Bs[buf][slot * 8] = rb[s];
    }
  };
  f32x4 z4 = {0.f,0.f,0.f,0.f};
  f32x4 acc[2][2] = {{z4,z4},{z4,z4}};
  issue(0); store(0);
  __syncthreads();
  int cur = 0;
  for (int kt = 0; kt < nt; ++kt) {
    bool more = (kt + 1 < nt);
    if (more) issue(kt + 1);
    #pragma unroll
    for (int kk = 0; kk < 2; ++kk) {
      int ko = kk * 4 + (lane >> 4);
      short8 af[2], bfr[2];
      #pragma unroll
      for (int f = 0; f < 2; ++f) {
        int row = wr * 32 + f * 16 + (lane & 15);
        af[f] = *(const short8*)&As[cur][(ko * 64 + row) * 8];
        int col = wc * 32 + f * 16 + (lane & 15);
        bfr[f] = *(const short8*)&Bs[cur][(ko * 64 + col) * 8];
      }
      #pragma unroll
      for (int i = 0; i < 2; ++i)
        #pragma unroll
        for (int j = 0; j < 2; ++j)
          acc[i][j] = __builtin_amdgcn_mfma_f32_16x16x32_bf16(af[i], bfr[j], acc[i][j], 0, 0, 0);
    }
    if (more) store(cur ^ 1);
    __syncthreads();
    cur ^= 1;
  }
  #pragma unroll
  for (int i = 0; i < 2; ++i)
    #pragma unroll
    for (int j = 0; j < 2; ++j)
      #pragma unroll
      for (int r = 0; r < 4; ++r) {
        int row = mBase + wr * 32 + i * 16 + (lane >> 4) * 4 + r;
        int col = nBase + wc * 32 + j * 16 + (lane & 15);
        Cb[(size_t)row * ldc + col] = f2bf(acc[i][j][r]);
      }
}

// ---------------- core 64x64 MFMA tile engine (device side) ----------------
template <class FA, class FE>
__device__ __forceinline__ void gemm_core(char* smem, FA loadA,
    const ushort_t* Bp, int Ntot, int nBase, int ktBeg, int ktEnd, FE epi)
{
  short* As = (short*)smem;
  short* Bs = (short*)smem + 8192;
  const int tid = threadIdx.x;
  const int lane = tid & 63, w = tid >> 6;
  const int wr = w >> 1, wc = w & 1;
  f32x4 z4 = {0.f,0.f,0.f,0.f};
  f32x4 acc[2][2] = {{z4,z4},{z4,z4}};
  short8 pa[2], pb[2];
  auto issue = [&](int kt) {
    #pragma unroll
    for (int s = 0; s < 2; ++s) {
      int slot = tid + s * 256;
      int kc = slot >> 6;
      int k = (kt << 6) + (kc << 3);
      pa[s] = loadA(slot & 63, k);
      int n = slot & 63;
      pb[s] = *(const short8*)(Bp + ((size_t)(k >> 3) * Ntot + nBase + n) * 8);
    }
  };
  auto store = [&](int buf) {
    #pragma unroll
    for (int s = 0; s < 2; ++s) {
      int slot = tid + s * 256;
      *(short8*)&As[buf * 4096 + slot * 8] = pa[s];
      *(short8*)&Bs[buf * 4096 + slot * 8] = pb[s];
    }
  };
  issue(ktBeg); store(0);
  __syncthreads();
  int cur = 0;
  for (int kt = ktBeg; kt < ktEnd; ++kt) {
    bool more = (kt + 1 < ktEnd);
    if (more) issue(kt + 1);
    #pragma unroll
    for (int kk = 0; kk < 2; ++kk) {
      int ko = kk * 4 + (lane >> 4);
      short8 af[2], bfr[2];
      #pragma unroll
      for (int f = 0; f < 2; ++f) {
        int row = wr * 32 + f * 16 + (lane & 15);
        af[f] = *(const short8*)&As[cur * 4096 + (ko * 64 + row) * 8];
        int col = wc * 32 + f * 16 + (lane & 15);
        bfr[f] = *(const short8*)&Bs[cur * 4096 + (ko * 64 + col) * 8];
      }
      #pragma unroll
      for (int i = 0; i < 2; ++i)
        #pragma unroll
        for (int j = 0; j < 2; ++j)
          acc[i][j] = __builtin_amdgcn_mfma_f32_16x16x32_bf16(af[i], bfr[j], acc[i][j], 0, 0, 0);
    }
    if (more) store(cur ^ 1);
    __syncthreads();
    cur ^= 1;
  }
  #pragma unroll
  for (int i = 0; i < 2; ++i)
    #pragma unroll
    for (int j = 0; j < 2; ++j)
      #pragma unroll
      for (int r = 0; r < 4; ++r) {
        int rl = wr * 32 + i * 16 + (lane >> 4) * 4 + r;
        int cl = wc * 32 + j * 16 + (lane & 15);
        epi(rl, cl, acc[i][j][r]);
      }
}

// ---------------- attention phase ----------------
struct SmemD { float ml[4][2]; float cs[4][DENC]; };
__device__ void phase_attn(int b, const float* __restrict__ enc,
    const float* __restrict__ attq, const int* __restrict__ enc_lens,
    ushort_t* __restrict__ ctxb, char* smem)
{
  int tid = threadIdx.x, w = tid >> 6, lane = tid & 63;
  int el = enc_lens[b];
  float q[8];
  const float* qp = attq + (size_t)b * DENC + lane * 8;
  #pragma unroll
  for (int j = 0; j < 8; ++j) q[j] = qp[j];
  float m = -1e30f, lr = 0.f;
  float cacc[8];
  #pragma unroll
  for (int j = 0; j < 8; ++j) cacc[j] = 0.f;
  const float* eb = enc + (size_t)b * NS * DENC + lane * 8;
  for (int s = w; s < el; s += 4) {
    float ev[8];
    ld8(eb + (size_t)s * DENC, ev);
    float d = 0.f;
    #pragma unroll
    for (int j = 0; j < 8; ++j) d = fmaf(ev[j], q[j], d);
    #pragma unroll
    for (int off = 32; off > 0; off >>= 1) d += __shfl_xor(d, off);
    float mn = fmaxf(m, d);
    float rr = __expf(m - mn), p = __expf(d - mn);
    lr = lr * rr + p;
    #pragma unroll
    for (int j = 0; j < 8; ++j) cacc[j] = cacc[j] * rr + p * ev[j];
    m = mn;
  }
  SmemD* sd = (SmemD*)smem;
  if (lane == 0) { sd->ml[w][0] = m; sd->ml[w][1] = lr; }
  #pragma unroll
  for (int j = 0; j < 8; ++j) sd->cs[w][lane * 8 + j] = cacc[j];
  __syncthreads();
  float M = fmaxf(fmaxf(sd->ml[0][0], sd->ml[1][0]), fmaxf(sd->ml[2][0], sd->ml[3][0]));
  float f0 = __expf(sd->ml[0][0] - M), f1 = __expf(sd->ml[1][0] - M);
  float f2 = __expf(sd->ml[2][0] - M), f3 = __expf(sd->ml[3][0] - M);
  float invL = 1.f / (f0 * sd->ml[0][1] + f1 * sd->ml[1][1] + f2 * sd->ml[2][1] + f3 * sd->ml[3][1]);
  #pragma unroll
  for (int rep = 0; rep < 2; ++rep) {
    int d = tid + rep * 256;
    ctxb[(size_t)b * DENC + d] =
        f2bf((f0 * sd->cs[0][d] + f1 * sd->cs[1][d] + f2 * sd->cs[2][d] + f3 * sd->cs[3][d]) * invL);
  }
}

// ---------------- final phase ----------------
struct SmemH { float eq[DACT]; float pq[DATT]; float av[DATT]; float logits[98]; float wl[NCOL]; float sgate; };
__device__ void phase_final(int b, char* smem,
    const float* __restrict__ embqP, const float* __restrict__ b_r2,
    const float* __restrict__ prod_embed, const float* __restrict__ b_lin,
    const ushort_t* __restrict__ attb, const float* __restrict__ ptrq,
    const float* __restrict__ col_enc, const float* __restrict__ w_mem,
    const int* __restrict__ col_lens, const int* __restrict__ tgt_lens,
    const int* __restrict__ action_kind, const int* __restrict__ prod_ids,
    const int* __restrict__ col_ids, float* __restrict__ appear,
    float* __restrict__ acc, int t)
{
  SmemH* sh = (SmemH*)smem;
  int tid = threadIdx.x;
  if (tid < DACT) {
    float v = b_r2[tid];
    #pragma unroll
    for (int p = 0; p < 4; ++p) v += embqP[(size_t)p * 32768 + b * DACT + tid];
    sh->eq[tid] = v;
  }
  for (int j = tid; j < DATT; j += 256) {
    sh->pq[j] = ptrq[(size_t)b * DATT + j];
    sh->av[j] = bf2f(attb[(size_t)b * DATT + j]);
  }
  __syncthreads();
  if (tid < 98) {
    const float* pr = prod_embed + tid * DACT;
    float a = 0.0f;
    #pragma unroll 8
    for (int k = 0; k < DACT; ++k) a = fmaf(sh->eq[k], pr[k], a);
    sh->logits[tid] = a + b_lin[tid];
  }
  {
    int wave = tid >> 6, lane = tid & 63;
    const float* cb = col_enc + (size_t)b * NCOL * 512;
    for (int ci = wave; ci < NCOL; ci += 4) {
      const float* e = cb + (size_t)ci * 512;
      float a = 0.0f;
      #pragma unroll
      for (int u = 0; u < 8; ++u) { int d = u * 64 + lane; a = fmaf(e[d], sh->pq[d], a); }
      #pragma unroll
      for (int off = 32; off > 0; off >>= 1) a += __shfl_down(a, off);
      if (lane == 0) sh->wl[ci] = a;
    }
  }
  if (tid < 64) {
    float a = 0.0f;
    #pragma unroll
    for (int u = 0; u < 8; ++u) { int d = u * 64 + tid; a = fmaf(sh->av[d], w_mem[d], a); }
    #pragma unroll
    for (int off = 32; off > 0; off >>= 1) a += __shfl_down(a, off);
    if (tid == 0) sh->sgate = sigf(a);
  }
  __syncthreads();
  if (tid < 64) {
    float m = sh->logits[tid];
    if (tid + 64 < 98) m = fmaxf(m, sh->logits[tid + 64]);
    #pragma unroll
    for (int off = 32; off > 0; off >>= 1) m = fmaxf(m, __shfl_down(m, off));
    m = __shfl(m, 0);
    float s = __expf(sh->logits[tid] - m) + ((tid + 64 < 98) ? __expf(sh->logits[tid + 64] - m) : 0.0f);
    #pragma unroll
    for (int off = 32; off > 0; off >>= 1) s += __shfl_down(s, off);
    s = __shfl(s, 0);
    float lseR = m + __logf(s);
    int clen = col_lens[b];
    float gate = sh->sgate;
    float ap = appear[b * NCOL + tid];
    float wv = sh->wl[tid] * (ap * gate + (1.0f - ap) * (1.0f - gate));
    wv = (tid < clen) ? wv : NEGV;
    sh->wl[tid] = wv;
    float m2 = wv;
    #pragma unroll
    for (int off = 32; off > 0; off >>= 1) m2 = fmaxf(m2, __shfl_down(m2, off));
    m2 = __shfl(m2, 0);
    float s2 = __expf(wv - m2);
    #pragma unroll
    for (int off = 32; off > 0; off >>= 1) s2 += __shfl_down(s2, off);
    s2 = __shfl(s2, 0);
    float lse2 = m2 + __logf(s2);
    float csum = (tid < clen) ? (wv - lse2) : 0.0f;
    #pragma unroll
    for (int off = 32; off > 0; off >>= 1) csum += __shfl_down(csum, off);
    if (tid == 0) {
      int kind = action_kind[b * NT + t];
      int pid = prod_ids[b * NT + t];
      int cid = col_ids[b * NT + t];
      bool valid = (t < tgt_lens[b]);
      int gj = (kind == 1) ? 97 : pid;
      float lp_rule = sh->logits[gj] - lseR;
      float lp_col = 0.8f * (sh->wl[cid] - lse2) + 0.2f * csum / (float)clen;
      float lp = (kind == 2) ? lp_col : lp_rule;
      if (valid) acc[b] += lp;
      if (kind == 2 && valid)
        appear[b * NCOL + cid] = fmaxf(appear[b * NCOL + cid], 1.0f);
    }
  }
}

// ---------------- the persistent decoder kernel ----------------
__global__ __launch_bounds__(256) void decoder_persistent(
    const float* __restrict__ enc, const float* __restrict__ col_enc,
    const int* __restrict__ enc_lens, const int* __restrict__ col_lens,
    const int* __restrict__ action_kind, const int* __restrict__ tgt_lens,
    const int* __restrict__ prod_ids, const int* __restrict__ col_ids,
    const int* __restrict__ parent_prod, const int* __restrict__ parent_type,
    const int* __restrict__ parent_time,
    const float* __restrict__ prod_embed, const float* __restrict__ type_embed,
    const float* __restrict__ b_lin, const float* __restrict__ b_lstm,
    const float* __restrict__ b_r1, const float* __restrict__ b_r2,
    const float* __restrict__ w_mem,
    const ushort_t* __restrict__ WpG, const ushort_t* __restrict__ WpQ,
    const ushort_t* __restrict__ WpV, const ushort_t* __restrict__ WpRP,
    const ushort_t* __restrict__ WpR2,
    float* cA, float* cB, float* attq, float* gates0, float* gates1,
    float* ptrq, float* embqP, ushort_t* hist_u, const ushort_t* colin_b,
    ushort_t* ctxb, ushort_t* attb, ushort_t* r1b,
    unsigned* bar, float* appear, float* acc, float* out)
{
  __shared__ __align__(16) char smem[32768];
  const int vb = blockIdx.x;

  for (int t = 0; t < NT; ++t) {
    float* c_in  = (t & 1) ? cB : cA;
    float* c_out = (t & 1) ? cA : cB;

    // ---- phase B: gates GEMM with fused input gather, split-K x2 ----
    {
      int tile = vb & 127, ks = vb >> 7;
      int mb = tile >> 5, nb = tile & 31;
      int mBase = mb * 64, nBase = nb * 64;
      float* gp = ks ? gates1 : gates0;
      int ktBeg = ks ? 15 : 0, ktEnd = ks ? 29 : 15;
      auto loadA = [&](int m_, int k) -> short8 {
        short8 z = {0,0,0,0,0,0,0,0};
        if (t == 0) return z;
        int b = mBase + m_;
        if (k < 128) {
          if (!((t - 1) < tgt_lens[b])) return z;
          int kp = action_kind[b * NT + t - 1];
          if (kp == 2) {
            int cp = col_ids[b * NT + t - 1];
            return *(const short8*)(colin_b + ((size_t)(b * NCOL + cp) * DACT + k));
          }
          int row = (kp == 1) ? 97 : prod_ids[b * NT + t - 1];
          return cvt8(prod_embed + (size_t)row * DACT + k);
        } else if (k < 640) {
          return *(const short8*)(attb + (size_t)b * DATT + (k - 128));
        } else if (k < 768) {
          int fp = parent_prod[b * NT + t];
          return cvt8(prod_embed + (size_t)fp * DACT + (k - 640));
        } else if (k < 832) {
          int ft = parent_type[b * NT + t];
          return cvt8(type_embed + (size_t)ft * DTYP + (k - 768));
        } else if (k < 1344) {
          int ptm = parent_time[b * NT + t];
          return *(const short8*)(hist_u + (size_t)ptm * NBH + (size_t)b * DRNN + (k - 832));
        } else {
          return *(const short8*)(hist_u + (size_t)(t - 1) * NBH + (size_t)b * DRNN + (k - 1344));
        }
      };
      auto epi = [&](int rl, int cl, float v) {
        gp[(size_t)(mBase + rl) * DG + nBase + cl] = v;
      };
      gemm_core(smem, loadA, WpG, DG, nBase, ktBeg, ktEnd, epi);
    }
    gbar(bar);

    // ---- phase C: attq GEMM, LSTM fused into A-staging ----
    if (vb < 32) {
      int mb = vb >> 3, nb = vb & 7;
      int mBase = mb * 64, nBase = nb * 64;
      bool writer = (nb == 0);
      auto loadA = [&](int m_, int k) -> short8 {
        int b = mBase + m_;
        const float* g0 = gates0 + (size_t)b * DG + k;
        const float* g1 = gates1 + (size_t)b * DG + k;
        float t0[8], t1[8], gi[8], gf[8], gg[8], go[8], cold[8];
        ld8(g0, t0); ld8(g1, t1);
        #pragma unroll
        for (int e = 0; e < 8; ++e) gi[e] = t0[e] + t1[e] + b_lstm[k + e];
        ld8(g0 + 512, t0); ld8(g1 + 512, t1);
        #pragma unroll
        for (int e = 0; e < 8; ++e) gf[e] = t0[e] + t1[e] + b_lstm[512 + k + e];
        ld8(g0 + 1024, t0); ld8(g1 + 1024, t1);
        #pragma unroll
        for (int e = 0; e < 8; ++e) gg[e] = t0[e] + t1[e] + b_lstm[1024 + k + e];
        ld8(g0 + 1536, t0); ld8(g1 + 1536, t1);
        #pragma unroll
        for (int e = 0; e < 8; ++e) go[e] = t0[e] + t1[e] + b_lstm[1536 + k + e];
        ld8(c_in + (size_t)b * DRNN + k, cold);
        short8 r;
        #pragma unroll
        for (int e = 0; e < 8; ++e) {
          float cn = sigf(gf[e]) * cold[e] + sigf(gi[e]) * tanhfast(gg[e]);
          float hn = sigf(go[e]) * tanhfast(cn);
          if (writer) {
            c_out[(size_t)b * DRNN + k + e] = cn;
            hist_u[(size_t)t * NBH + (size_t)b * DRNN + k + e] = f2bf(hn);
          }
          r[e] = (short)f2bf(hn);
        }
        return r;
      };
      auto epi = [&](int rl, int cl, float v) {
        attq[(size_t)(mBase + rl) * DENC + nBase + cl] = v;
      };
      gemm_core(smem, loadA, WpQ, 512, nBase, 0, 8, epi);
    }
    gbar(bar);

    // ---- phase D: attention ----
    phase_attn(vb, enc, attq, enc_lens, ctxb, smem);
    gbar(bar);

    // ---- phase E: attvec GEMM ----
    if (vb < 32) {
      int mb = vb >> 3, nb = vb & 7;
      int mBase = mb * 64, nBase = nb * 64;
      auto loadA = [&](int m_, int k) -> short8 {
        int b = mBase + m_;
        if (k < 512) return *(const short8*)(ctxb + (size_t)b * DENC + k);
        return *(const short8*)(hist_u + (size_t)t * NBH + (size_t)b * DRNN + (k - 512));
      };
      auto epi = [&](int rl, int cl, float v) {
        attb[(size_t)(mBase + rl) * DATT + nBase + cl] = f2bf(tanhfast(v));
      };
      gemm_core(smem, loadA, WpV, 512, nBase, 0, 16, epi);
    }
    gbar(bar);

    // ---- phase F: [r1|ptr] GEMM ----
    if (vb < 160) {
      int mb = vb / 40, nb = vb % 40;
      int mBase = mb * 64, nBase = nb * 64;
      auto loadA = [&](int m_, int k) -> short8 {
        int b = mBase + m_;
        return *(const short8*)(attb + (size_t)b * DATT + k);
      };
      auto epi = [&](int rl, int cl, float v) {
        int col = nBase + cl;
        int row = mBase + rl;
        if (col < 2048) r1b[(size_t)row * DG + col] = f2bf(tanhfast(v + b_r1[col]));
        else            ptrq[(size_t)row * 512 + (col - 2048)] = v;
      };
      gemm_core(smem, loadA, WpRP, 2560, nBase, 0, 8, epi);
    }
    gbar(bar);

    // ---- phase G: r2 GEMM, split-K x4 ----
    if (vb < 32) {
      int tile = vb & 7, ks = vb >> 3;
      int mb = tile >> 1, nb = tile & 1;
      int mBase = mb * 64, nBase = nb * 64;
      auto loadA = [&](int m_, int k) -> short8 {
        int b = mBase + m_;
        return *(const short8*)(r1b + (size_t)b * DG + k);
      };
      auto epi = [&](int rl, int cl, float v) {
        embqP[(size_t)ks * 32768 + (size_t)(mBase + rl) * DACT + nBase + cl] = v;
      };
      gemm_core(smem, loadA, WpR2, DACT, nBase, ks * 8, ks * 8 + 8, epi);
    }
    gbar(bar);

    // ---- phase H: readout / pointer / loss accumulation ----
    phase_final(vb, smem, embqP, b_r2, prod_embed, b_lin, attb, ptrq,
                col_enc, w_mem, col_lens, tgt_lens, action_kind, prod_ids,
                col_ids, appear, acc, t);
    gbar(bar);
  }

  if (vb == 0) {
    int tid = threadIdx.x;
    float v = acc[tid];
    #pragma unroll
    for (int off = 32; off > 0; off >>= 1) v += __shfl_down(v, off);
    float* part = (float*)smem;
    if ((tid & 63) == 0) part[tid >> 6] = v;
    __syncthreads();
    if (tid == 0) out[0] = -(part[0] + part[1] + part[2] + part[3]) * (1.0f / NB);
  }
}

// -------------------------------------------------------------------------
extern "C" void kernel_launch(void* const* d_in, const int* in_sizes, int n_in,
                              void* d_out, int out_size, void* d_ws, size_t ws_size,
                              hipStream_t stream) {
  const float* enc         = (const float*)d_in[0];
  const float* col_enc     = (const float*)d_in[1];
  const int*   enc_lens    = (const int*)d_in[2];
  const int*   col_lens    = (const int*)d_in[3];
  const int*   action_kind = (const int*)d_in[4];
  const int*   tgt_lens    = (const int*)d_in[5];
  const int*   prod_ids    = (const int*)d_in[6];
  const int*   col_ids     = (const int*)d_in[7];
  const int*   parent_prod = (const int*)d_in[8];
  const int*   parent_type = (const int*)d_in[9];
  const int*   parent_time = (const int*)d_in[10];
  const float* prod_embed  = (const float*)d_in[11];
  const float* type_embed  = (const float*)d_in[12];
  const float* b_lin       = (const float*)d_in[13];
  const float* W_ih        = (const float*)d_in[14];
  const float* W_hh        = (const float*)d_in[15];
  const float* b_lstm      = (const float*)d_in[16];
  const float* W_att_q     = (const float*)d_in[17];
  const float* W_att_vec   = (const float*)d_in[18];
  const float* W_r1        = (const float*)d_in[19];
  const float* b_r1        = (const float*)d_in[20];
  const float* W_r2        = (const float*)d_in[21];
  const float* b_r2        = (const float*)d_in[22];
  const float* W_col_in    = (const float*)d_in[23];
  const float* W_ptr       = (const float*)d_in[24];
  const float* w_mem       = (const float*)d_in[25];

  float* base = (float*)d_ws;
  size_t o = 0;
  float* cA     = base + o; o += 131072;
  float* appear = base + o; o += 16384;
  float* acc    = base + o; o += 256;
  unsigned* bar = (unsigned*)(base + o); o += 64;
  int zeroN = (int)o;
  float* cB     = base + o; o += 131072;
  float* attq   = base + o; o += 131072;
  float* gates0 = base + o; o += 524288;
  float* gates1 = base + o; o += 524288;
  float* ptrq   = base + o; o += 131072;
  float* embqP  = base + o; o += 131072;
  ushort_t* hist_u  = (ushort_t*)(base + o); o += 3932160;
  ushort_t* colin_b = (ushort_t*)(base + o); o += 1048576;
  ushort_t* ctxb    = (ushort_t*)(base + o); o += 32768;
  ushort_t* attb    = (ushort_t*)(base + o); o += 32768;
  ushort_t* r1b     = (ushort_t*)(base + o); o += 262144;
  ushort_t* WpG  = (ushort_t*)(base + o); o += 1900544;
  ushort_t* WpQ  = (ushort_t*)(base + o); o += 131072;
  ushort_t* WpV  = (ushort_t*)(base + o); o += 262144;
  ushort_t* WpRP = (ushort_t*)(base + o); o += 655360;
  ushort_t* WpR2 = (ushort_t*)(base + o); o += 131072;
  ushort_t* WpCI = (ushort_t*)(base + o); o += 32768;
  (void)ws_size; (void)in_sizes; (void)n_in; (void)out_size;

  zero_kernel<<<(zeroN + 255) / 256, 256, 0, stream>>>(base, zeroN);

  pack_w<<<(1344 * 2048 + 255) / 256, 256, 0, stream>>>(W_ih,  WpG, 1344, 2048, 2048, 0, 0, 2048);
  pack_w<<<(512 * 2048 + 255) / 256, 256, 0, stream>>>(W_hh,  WpG,  512, 2048, 2048, 1344, 0, 2048);
  pack_w<<<(512 * 512 + 255) / 256, 256, 0, stream>>>(W_att_q, WpQ, 512, 512, 512, 0, 0, 512);
  pack_w<<<(1024 * 512 + 255) / 256, 256, 0, stream>>>(W_att_vec, WpV, 1024, 512, 512, 0, 0, 512);
  pack_w<<<(512 * 2048 + 255) / 256, 256, 0, stream>>>(W_r1,  WpRP, 512, 2048, 2560, 0, 0, 2048);
  pack_w<<<(512 * 512 + 255) / 256, 256, 0, stream>>>(W_ptr, WpRP, 512, 512, 2560, 0, 2048, 512);
  pack_w<<<(2048 * 128 + 255) / 256, 256, 0, stream>>>(W_r2,  WpR2, 2048, 128, 128, 0, 0, 128);
  pack_w<<<(512 * 128 + 255) / 256, 256, 0, stream>>>(W_col_in, WpCI, 512, 128, 128, 0, 0, 128);

  // colin = col_enc @ W_col_in -> bf16  (M=16384, K=512, N=128)
  gemm_bf16<<<dim3(2, 256), 256, 0, stream>>>(col_enc, 512, WpCI, colin_b, 128, 128, 512);

  decoder_persistent<<<NBLK, 256, 0, stream>>>(
      enc, col_enc, enc_lens, col_lens, action_kind, tgt_lens, prod_ids,
      col_ids, parent_prod, parent_type, parent_time, prod_embed, type_embed,
      b_lin, b_lstm, b_r1, b_r2, w_mem,
      WpG, WpQ, WpV, WpRP, WpR2,
      cA, cB, attq, gates0, gates1, ptrq, embqP, hist_u, colin_b,
      ctxb, attb, r1b, bar, appear, acc, (float*)d_out);
}

// Round 4
// 7644.281 us; speedup vs baseline: 9.1083x; 9.1083x over previous
//
#include <hip/hip_runtime.h>
#include <math.h>

#define NB 256
#define NS 128
#define NCOL 64
#define NT 60
#define DENC 512
#define DRNN 512
#define DATT 512
#define DACT 128
#define DTYP 64
#define DG 2048
#define NEGV (-1e9f)
#define NBH 131072   // NB*DRNN (elements per hist step)

typedef unsigned short ushort_t;
typedef __attribute__((ext_vector_type(8))) short short8;
typedef __attribute__((ext_vector_type(4))) float f32x4;

__device__ __forceinline__ float sigf(float x) { return 1.0f / (1.0f + __expf(-x)); }
__device__ __forceinline__ float tanhfast(float x) {
  x = fminf(fmaxf(x, -15.0f), 15.0f);
  float e = __expf(-2.0f * x);
  return (1.0f - e) / (1.0f + e);
}
__device__ __forceinline__ ushort_t f2bf(float f) {
  union { float f; unsigned u; } v; v.f = f;
  unsigned r = v.u + 0x7fffu + ((v.u >> 16) & 1u);
  return (ushort_t)(r >> 16);
}
__device__ __forceinline__ float bf2f(ushort_t b) {
  union { unsigned u; float f; } v; v.u = ((unsigned)b) << 16; return v.f;
}
__device__ __forceinline__ void ld8(const float* p, float* d) {
  f32x4 x = *(const f32x4*)p, y = *(const f32x4*)(p + 4);
  d[0]=x[0]; d[1]=x[1]; d[2]=x[2]; d[3]=x[3];
  d[4]=y[0]; d[5]=y[1]; d[6]=y[2]; d[7]=y[3];
}
__device__ __forceinline__ short8 cvt8(const float* p) {
  f32x4 x = *(const f32x4*)p, y = *(const f32x4*)(p + 4);
  short8 r;
  r[0]=(short)f2bf(x[0]); r[1]=(short)f2bf(x[1]); r[2]=(short)f2bf(x[2]); r[3]=(short)f2bf(x[3]);
  r[4]=(short)f2bf(y[0]); r[5]=(short)f2bf(y[1]); r[6]=(short)f2bf(y[2]); r[7]=(short)f2bf(y[3]);
  return r;
}

// -------------------------------------------------------------------------
__global__ __launch_bounds__(256) void zero_kernel(float* __restrict__ p, int n) {
  int i = blockIdx.x * 256 + threadIdx.x;
  if (i < n) p[i] = 0.0f;
}

// pack f32 weight into bf16 [(K/8)][Ntot][8]
__global__ __launch_bounds__(256) void pack_w(const float* __restrict__ src,
    ushort_t* __restrict__ dst, int Ksub, int Nsub, int Ntot, int K0, int N0, int ldsrc)
{
  int idx = blockIdx.x * 256 + threadIdx.x;
  if (idx >= Ksub * Nsub) return;
  int k = idx / Nsub, n = idx - k * Nsub;
  int gk = K0 + k;
  dst[((size_t)(gk >> 3) * Ntot + (N0 + n)) * 8 + (gk & 7)] =
      f2bf(src[(size_t)k * ldsrc + n]);
}

// gate-interleaved pack for the LSTM weight: orig col n = q*512+j -> packed 4j+q
__global__ __launch_bounds__(256) void pack_w_perm(const float* __restrict__ src,
    ushort_t* __restrict__ dst, int Ksub, int K0)
{
  int idx = blockIdx.x * 256 + threadIdx.x;
  if (idx >= Ksub * DG) return;
  int k = idx / DG, n = idx - k * DG;
  int gk = K0 + k;
  int nperm = 4 * (n & 511) + (n >> 9);
  dst[((size_t)(gk >> 3) * DG + nperm) * 8 + (gk & 7)] =
      f2bf(src[(size_t)k * DG + n]);
}

// W_r2p[k][j] = sum_d W_r2[k][d]*prod_embed[j][d]; bias2[j] = b_r2.pe[j]+b_lin[j]
__global__ __launch_bounds__(256) void r2p_kernel(const float* __restrict__ W_r2,
    const float* __restrict__ prod_embed, const float* __restrict__ b_r2,
    const float* __restrict__ b_lin, ushort_t* __restrict__ Wr2p,
    float* __restrict__ bias2)
{
  int idx = blockIdx.x * 256 + threadIdx.x;
  if (idx >= 2049 * 98) return;
  int k = idx / 98, j = idx - k * 98;
  const float* pe = prod_embed + (size_t)j * DACT;
  if (k < 2048) {
    const float* wr = W_r2 + (size_t)k * DACT;
    float a = 0.f;
    #pragma unroll 8
    for (int d = 0; d < DACT; ++d) a = fmaf(wr[d], pe[d], a);
    Wr2p[(size_t)k * 112 + j] = f2bf(a);
  } else {
    float a = b_lin[j];
    #pragma unroll 8
    for (int d = 0; d < DACT; ++d) a = fmaf(b_r2[d], pe[d], a);
    bias2[j] = a;
  }
}

// standalone MFMA GEMM used once for colin (A f32)
__global__ __launch_bounds__(256) void gemm_bf16(
    const float* __restrict__ A1, int lda1,
    const ushort_t* __restrict__ Bp, ushort_t* __restrict__ Cb, int ldc,
    int N, int K)
{
  __shared__ short As[2][4096];
  __shared__ short Bs[2][4096];
  const int tid = threadIdx.x;
  const int lane = tid & 63, w = tid >> 6;
  const int wr = w >> 1, wc = w & 1;
  const int mBase = blockIdx.y * 64, nBase = blockIdx.x * 64;
  const int nt = K >> 6;
  f32x4 ra0[2], ra1[2];
  short8 rb[2];
  auto issue = [&](int kt) {
    #pragma unroll
    for (int s = 0; s < 2; ++s) {
      int slot = tid + s * 256;
      int kc = slot >> 6, m = slot & 63;
      int k0 = (kt << 6) + kc * 8;
      const float* p = A1 + (size_t)(mBase + m) * lda1 + k0;
      ra0[s] = *(const f32x4*)p;
      ra1[s] = *(const f32x4*)(p + 4);
      rb[s] = *(const short8*)(Bp + ((size_t)(k0 >> 3) * N + nBase + m) * 8);
    }
  };
  auto store = [&](int buf) {
    #pragma unroll
    for (int s = 0; s < 2; ++s) {
      int slot = tid + s * 256;
      short8 av;
      av[0]=(short)f2bf(ra0[s][0]); av[1]=(short)f2bf(ra0[s][1]);
      av[2]=(short)f2bf(ra0[s][2]); av[3]=(short)f2bf(ra0[s][3]);
      av[4]=(short)f2bf(ra1[s][0]); av[5]=(short)f2bf(ra1[s][1]);
      av[6]=(short)f2bf(ra1[s][2]); av[7]=(short)f2bf(ra1[s][3]);
      *(short8*)&As[buf][slot * 8] = av;
      *(short8*)&Bs[buf][slot * 8] = rb[s];
    }
  };
  f32x4 z4 = {0.f,0.f,0.f,0.f};
  f32x4 acc[2][2] = {{z4,z4},{z4,z4}};
  issue(0); store(0);
  __syncthreads();
  int cur = 0;
  for (int kt = 0; kt < nt; ++kt) {
    bool more = (kt + 1 < nt);
    if (more) issue(kt + 1);
    #pragma unroll
    for (int kk = 0; kk < 2; ++kk) {
      int ko = kk * 4 + (lane >> 4);
      short8 af[2], bfr[2];
      #pragma unroll
      for (int f = 0; f < 2; ++f) {
        int row = wr * 32 + f * 16 + (lane & 15);
        af[f] = *(const short8*)&As[cur][(ko * 64 + row) * 8];
        int col = wc * 32 + f * 16 + (lane & 15);
        bfr[f] = *(const short8*)&Bs[cur][(ko * 64 + col) * 8];
      }
      #pragma unroll
      for (int i = 0; i < 2; ++i)
        #pragma unroll
        for (int j = 0; j < 2; ++j)
          acc[i][j] = __builtin_amdgcn_mfma_f32_16x16x32_bf16(af[i], bfr[j], acc[i][j], 0, 0, 0);
    }
    if (more) store(cur ^ 1);
    __syncthreads();
    cur ^= 1;
  }
  #pragma unroll
  for (int i = 0; i < 2; ++i)
    #pragma unroll
    for (int j = 0; j < 2; ++j)
      #pragma unroll
      for (int r = 0; r < 4; ++r) {
        int row = mBase + wr * 32 + i * 16 + (lane >> 4) * 4 + r;
        int col = nBase + wc * 32 + j * 16 + (lane & 15);
        Cb[(size_t)row * ldc + col] = f2bf(acc[i][j][r]);
      }
}

// ---------------- core 64x64 MFMA tile engine (device side) ----------------
template <class FA, class FE>
__device__ __forceinline__ void gemm_core(char* smem, FA loadA,
    const ushort_t* Bp, int Ntot, int nBase, int ktBeg, int ktEnd, FE epi)
{
  short* As = (short*)smem;
  short* Bs = (short*)smem + 8192;
  const int tid = threadIdx.x;
  const int lane = tid & 63, w = tid >> 6;
  const int wr = w >> 1, wc = w & 1;
  f32x4 z4 = {0.f,0.f,0.f,0.f};
  f32x4 acc[2][2] = {{z4,z4},{z4,z4}};
  short8 pa[2], pb[2];
  auto issue = [&](int kt) {
    #pragma unroll
    for (int s = 0; s < 2; ++s) {
      int slot = tid + s * 256;
      int kc = slot >> 6;
      int k = (kt << 6) + (kc << 3);
      pa[s] = loadA(k);
      int n = slot & 63;
      pb[s] = *(const short8*)(Bp + ((size_t)(k >> 3) * Ntot + nBase + n) * 8);
    }
  };
  auto store = [&](int buf) {
    #pragma unroll
    for (int s = 0; s < 2; ++s) {
      int slot = tid + s * 256;
      *(short8*)&As[buf * 4096 + slot * 8] = pa[s];
      *(short8*)&Bs[buf * 4096 + slot * 8] = pb[s];
    }
  };
  issue(ktBeg); store(0);
  __syncthreads();
  int cur = 0;
  for (int kt = ktBeg; kt < ktEnd; ++kt) {
    bool more = (kt + 1 < ktEnd);
    if (more) issue(kt + 1);
    #pragma unroll
    for (int kk = 0; kk < 2; ++kk) {
      int ko = kk * 4 + (lane >> 4);
      short8 af[2], bfr[2];
      #pragma unroll
      for (int f = 0; f < 2; ++f) {
        int row = wr * 32 + f * 16 + (lane & 15);
        af[f] = *(const short8*)&As[cur * 4096 + (ko * 64 + row) * 8];
        int col = wc * 32 + f * 16 + (lane & 15);
        bfr[f] = *(const short8*)&Bs[cur * 4096 + (ko * 64 + col) * 8];
      }
      #pragma unroll
      for (int i = 0; i < 2; ++i)
        #pragma unroll
        for (int j = 0; j < 2; ++j)
          acc[i][j] = __builtin_amdgcn_mfma_f32_16x16x32_bf16(af[i], bfr[j], acc[i][j], 0, 0, 0);
    }
    if (more) store(cur ^ 1);
    __syncthreads();
    cur ^= 1;
  }
  #pragma unroll
  for (int i = 0; i < 2; ++i)
    #pragma unroll
    for (int j = 0; j < 2; ++j)
      #pragma unroll
      for (int r = 0; r < 4; ++r) {
        int rl = wr * 32 + i * 16 + (lane >> 4) * 4 + r;
        int cl = wc * 32 + j * 16 + (lane & 15);
        epi(rl, cl, acc[i][j][r]);
      }
}

// ---------------- K1: gates GEMM (fused gather) + LSTM epilogue ------------
__global__ __launch_bounds__(256) void k1_gates_lstm(
    const int* __restrict__ action_kind, const int* __restrict__ tgt_lens,
    const int* __restrict__ prod_ids, const int* __restrict__ col_ids,
    const int* __restrict__ parent_prod, const int* __restrict__ parent_type,
    const int* __restrict__ parent_time,
    const float* __restrict__ prod_embed, const float* __restrict__ type_embed,
    const float* __restrict__ b_lstm,
    const ushort_t* __restrict__ WpG, const ushort_t* __restrict__ colin_b,
    const ushort_t* __restrict__ attb, const ushort_t* __restrict__ hist_u,
    ushort_t* __restrict__ hist_t, float* __restrict__ cst, int t)
{
  __shared__ __align__(16) char smem[32768];
  const int tid = threadIdx.x;
  const int nb = blockIdx.x, mb = blockIdx.y;
  const int mBase = mb * 64, nBase = nb * 64;
  const int b = mBase + (tid & 63);
  int kp = 0, pp = 0, cp = 0, fp = 0, ft = 0, ptm = 0;
  bool pv = false;
  if (t > 0) {
    kp = action_kind[b * NT + t - 1];
    pp = prod_ids[b * NT + t - 1];
    cp = col_ids[b * NT + t - 1];
    pv = (t - 1) < tgt_lens[b];
    fp = parent_prod[b * NT + t];
    ft = parent_type[b * NT + t];
    ptm = parent_time[b * NT + t];
  }
  const ushort_t* hist_prev = hist_u + (size_t)(t - 1) * NBH;
  auto loadA = [&](int k) -> short8 {
    short8 z = {0,0,0,0,0,0,0,0};
    if (t == 0) return z;
    if (k < 128) {
      if (!pv) return z;
      if (kp == 2) return *(const short8*)(colin_b + ((size_t)(b * NCOL + cp) * DACT + k));
      int row = (kp == 1) ? 97 : pp;
      return cvt8(prod_embed + (size_t)row * DACT + k);
    } else if (k < 640) {
      return *(const short8*)(attb + (size_t)b * DATT + (k - 128));
    } else if (k < 768) {
      return cvt8(prod_embed + (size_t)fp * DACT + (k - 640));
    } else if (k < 832) {
      return cvt8(type_embed + (size_t)ft * DTYP + (k - 768));
    } else if (k < 1344) {
      return *(const short8*)(hist_u + (size_t)ptm * NBH + (size_t)b * DRNN + (k - 832));
    } else {
      return *(const short8*)(hist_prev + (size_t)b * DRNN + (k - 1344));
    }
  };
  float* sacc = (float*)smem;   // [64][69] aliases As/Bs after compute done
  auto epi = [&](int rl, int cl, float v) { sacc[rl * 69 + cl] = v; };
  gemm_core(smem, loadA, WpG, DG, nBase, 0, 29, epi);
  __syncthreads();
  // LSTM: tile covers channels nb*16 .. +16 for rows mBase..+64
  {
    int r = tid & 63;
    int qrow = tid >> 6;
    #pragma unroll
    for (int q4 = 0; q4 < 4; ++q4) {
      int jloc = qrow + q4 * 4;
      int j = nb * 16 + jloc;
      float gi = sacc[r * 69 + 4 * jloc + 0] + b_lstm[j];
      float gf = sacc[r * 69 + 4 * jloc + 1] + b_lstm[512 + j];
      float gg = sacc[r * 69 + 4 * jloc + 2] + b_lstm[1024 + j];
      float go = sacc[r * 69 + 4 * jloc + 3] + b_lstm[1536 + j];
      size_t ix = (size_t)b * DRNN + j;
      float cn = sigf(gf) * cst[ix] + sigf(gi) * tanhfast(gg);
      float hn = sigf(go) * tanhfast(cn);
      cst[ix] = cn;
      hist_t[ix] = f2bf(hn);
    }
  }
}

// ---------------- K2: attq = h @ W_att_q ----------------
__global__ __launch_bounds__(256) void k2_attq(const ushort_t* __restrict__ hist_t,
    const ushort_t* __restrict__ WpQ, float* __restrict__ attq)
{
  __shared__ __align__(16) char smem[32768];
  const int tid = threadIdx.x;
  const int mBase = blockIdx.y * 64, nBase = blockIdx.x * 64;
  const int b = mBase + (tid & 63);
  auto loadA = [&](int k) -> short8 {
    return *(const short8*)(hist_t + (size_t)b * DRNN + k);
  };
  auto epi = [&](int rl, int cl, float v) {
    attq[(size_t)(mBase + rl) * DENC + nBase + cl] = v;
  };
  gemm_core(smem, loadA, WpQ, 512, nBase, 0, 8, epi);
}

// ---------------- K3: online-softmax attention ----------------
struct SmemD { float ml[4][2]; float cs[4][DENC]; };
__global__ __launch_bounds__(256) void k3_attn(const float* __restrict__ enc,
    const float* __restrict__ attq, const int* __restrict__ enc_lens,
    ushort_t* __restrict__ ctxb)
{
  __shared__ __align__(16) SmemD sd;
  int b = blockIdx.x, tid = threadIdx.x;
  int w = tid >> 6, lane = tid & 63;
  int el = enc_lens[b];
  float q[8];
  const float* qp = attq + (size_t)b * DENC + lane * 8;
  #pragma unroll
  for (int j = 0; j < 8; ++j) q[j] = qp[j];
  float m = -1e30f, lr = 0.f;
  float cacc[8];
  #pragma unroll
  for (int j = 0; j < 8; ++j) cacc[j] = 0.f;
  const float* eb = enc + (size_t)b * NS * DENC + lane * 8;
  for (int s = w; s < el; s += 4) {
    float ev[8];
    ld8(eb + (size_t)s * DENC, ev);
    float d = 0.f;
    #pragma unroll
    for (int j = 0; j < 8; ++j) d = fmaf(ev[j], q[j], d);
    #pragma unroll
    for (int off = 32; off > 0; off >>= 1) d += __shfl_xor(d, off);
    float mn = fmaxf(m, d);
    float rr = __expf(m - mn), p = __expf(d - mn);
    lr = lr * rr + p;
    #pragma unroll
    for (int j = 0; j < 8; ++j) cacc[j] = cacc[j] * rr + p * ev[j];
    m = mn;
  }
  if (lane == 0) { sd.ml[w][0] = m; sd.ml[w][1] = lr; }
  #pragma unroll
  for (int j = 0; j < 8; ++j) sd.cs[w][lane * 8 + j] = cacc[j];
  __syncthreads();
  float M = fmaxf(fmaxf(sd.ml[0][0], sd.ml[1][0]), fmaxf(sd.ml[2][0], sd.ml[3][0]));
  float f0 = __expf(sd.ml[0][0] - M), f1 = __expf(sd.ml[1][0] - M);
  float f2 = __expf(sd.ml[2][0] - M), f3 = __expf(sd.ml[3][0] - M);
  float invL = 1.f / (f0 * sd.ml[0][1] + f1 * sd.ml[1][1] + f2 * sd.ml[2][1] + f3 * sd.ml[3][1]);
  #pragma unroll
  for (int rep = 0; rep < 2; ++rep) {
    int d = tid + rep * 256;
    ctxb[(size_t)b * DENC + d] =
        f2bf((f0 * sd.cs[0][d] + f1 * sd.cs[1][d] + f2 * sd.cs[2][d] + f3 * sd.cs[3][d]) * invL);
  }
}

// ---------------- K4: att = tanh([ctx|h] @ W_att_vec) ----------------
__global__ __launch_bounds__(256) void k4_attvec(const ushort_t* __restrict__ ctxb,
    const ushort_t* __restrict__ hist_t, const ushort_t* __restrict__ WpV,
    ushort_t* __restrict__ attb)
{
  __shared__ __align__(16) char smem[32768];
  const int tid = threadIdx.x;
  const int mBase = blockIdx.y * 64, nBase = blockIdx.x * 64;
  const int b = mBase + (tid & 63);
  auto loadA = [&](int k) -> short8 {
    if (k < 512) return *(const short8*)(ctxb + (size_t)b * DENC + k);
    return *(const short8*)(hist_t + (size_t)b * DRNN + (k - 512));
  };
  auto epi = [&](int rl, int cl, float v) {
    attb[(size_t)(mBase + rl) * DATT + nBase + cl] = f2bf(tanhfast(v));
  };
  gemm_core(smem, loadA, WpV, 512, nBase, 0, 16, epi);
}

// ---------------- K5: [r1|ptr] = att @ [W_r1|W_ptr] ----------------
__global__ __launch_bounds__(256) void k5_r1ptr(const ushort_t* __restrict__ attb,
    const ushort_t* __restrict__ WpRP, const float* __restrict__ b_r1,
    ushort_t* __restrict__ r1b, float* __restrict__ ptrq)
{
  __shared__ __align__(16) char smem[32768];
  const int tid = threadIdx.x;
  const int mBase = blockIdx.y * 64, nBase = blockIdx.x * 64;
  const int b = mBase + (tid & 63);
  auto loadA = [&](int k) -> short8 {
    return *(const short8*)(attb + (size_t)b * DATT + k);
  };
  auto epi = [&](int rl, int cl, float v) {
    int col = nBase + cl, row = mBase + rl;
    if (col < 2048) r1b[(size_t)row * DG + col] = f2bf(tanhfast(v + b_r1[col]));
    else            ptrq[(size_t)row * 512 + (col - 2048)] = v;
  };
  gemm_core(smem, loadA, WpRP, 2560, nBase, 0, 8, epi);
}

// ---------------- K6: logits matvec + pointer net + loss accum ----------------
__global__ __launch_bounds__(256) void k6_final(
    const ushort_t* __restrict__ r1b, const ushort_t* __restrict__ Wr2p,
    const float* __restrict__ bias2, const ushort_t* __restrict__ attb,
    const float* __restrict__ ptrq, const float* __restrict__ col_enc,
    const float* __restrict__ w_mem, const int* __restrict__ col_lens,
    const int* __restrict__ tgt_lens, const int* __restrict__ action_kind,
    const int* __restrict__ prod_ids, const int* __restrict__ col_ids,
    float* __restrict__ appear, float* __restrict__ acc, int t)
{
  __shared__ ushort_t sr1[2048];
  __shared__ float pq[DATT], av[DATT];
  __shared__ float lpart[2][98];
  __shared__ float logits[98];
  __shared__ float wl[NCOL];
  __shared__ float sgate;
  int b = blockIdx.x, tid = threadIdx.x;
  *(short8*)&sr1[tid * 8] = *(const short8*)(r1b + (size_t)b * DG + tid * 8);
  for (int j = tid; j < DATT; j += 256) {
    pq[j] = ptrq[(size_t)b * 512 + j];
    av[j] = bf2f(attb[(size_t)b * DATT + j]);
  }
  __syncthreads();
  // logits matvec: 2 k-halves x 98 cols
  {
    int col = -1, half = 0;
    if (tid < 98) { col = tid; half = 0; }
    else if (tid >= 128 && tid < 226) { col = tid - 128; half = 1; }
    if (col >= 0) {
      int k0 = half * 1024;
      const ushort_t* wp = Wr2p + (size_t)k0 * 112 + col;
      float a = 0.f;
      #pragma unroll 8
      for (int k = 0; k < 1024; ++k)
        a = fmaf(bf2f(sr1[k0 + k]), bf2f(wp[(size_t)k * 112]), a);
      lpart[half][col] = a;
    }
  }
  // pointer scores
  {
    int wave = tid >> 6, lane = tid & 63;
    const float* cb = col_enc + (size_t)b * NCOL * 512;
    for (int ci = wave; ci < NCOL; ci += 4) {
      const float* e = cb + (size_t)ci * 512;
      float a = 0.0f;
      #pragma unroll
      for (int u = 0; u < 8; ++u) { int d = u * 64 + lane; a = fmaf(e[d], pq[d], a); }
      #pragma unroll
      for (int off = 32; off > 0; off >>= 1) a += __shfl_down(a, off);
      if (lane == 0) wl[ci] = a;
    }
  }
  if (tid < 64) {
    float a = 0.0f;
    #pragma unroll
    for (int u = 0; u < 8; ++u) { int d = u * 64 + tid; a = fmaf(av[d], w_mem[d], a); }
    #pragma unroll
    for (int off = 32; off > 0; off >>= 1) a += __shfl_down(a, off);
    if (tid == 0) sgate = sigf(a);
  }
  __syncthreads();
  if (tid < 98) logits[tid] = lpart[0][tid] + lpart[1][tid] + bias2[tid];
  __syncthreads();
  if (tid < 64) {
    float m = logits[tid];
    if (tid + 64 < 98) m = fmaxf(m, logits[tid + 64]);
    #pragma unroll
    for (int off = 32; off > 0; off >>= 1) m = fmaxf(m, __shfl_down(m, off));
    m = __shfl(m, 0);
    float s = __expf(logits[tid] - m) + ((tid + 64 < 98) ? __expf(logits[tid + 64] - m) : 0.0f);
    #pragma unroll
    for (int off = 32; off > 0; off >>= 1) s += __shfl_down(s, off);
    s = __shfl(s, 0);
    float lseR = m + __logf(s);
    int clen = col_lens[b];
    float gate = sgate;
    float ap = appear[b * NCOL + tid];
    float wv = wl[tid] * (ap * gate + (1.0f - ap) * (1.0f - gate));
    wv = (tid < clen) ? wv : NEGV;
    wl[tid] = wv;
    float m2 = wv;
    #pragma unroll
    for (int off = 32; off > 0; off >>= 1) m2 = fmaxf(m2, __shfl_down(m2, off));
    m2 = __shfl(m2, 0);
    float s2 = __expf(wv - m2);
    #pragma unroll
    for (int off = 32; off > 0; off >>= 1) s2 += __shfl_down(s2, off);
    s2 = __shfl(s2, 0);
    float lse2 = m2 + __logf(s2);
    float csum = (tid < clen) ? (wv - lse2) : 0.0f;
    #pragma unroll
    for (int off = 32; off > 0; off >>= 1) csum += __shfl_down(csum, off);
    if (tid == 0) {
      int kind = action_kind[b * NT + t];
      int pid = prod_ids[b * NT + t];
      int cid = col_ids[b * NT + t];
      bool valid = (t < tgt_lens[b]);
      int gj = (kind == 1) ? 97 : pid;
      float lp_rule = logits[gj] - lseR;
      float lp_col = 0.8f * (wl[cid] - lse2) + 0.2f * csum / (float)clen;
      float lp = (kind == 2) ? lp_col : lp_rule;
      if (valid) acc[b] += lp;
      if (kind == 2 && valid)
        appear[b * NCOL + cid] = fmaxf(appear[b * NCOL + cid], 1.0f);
    }
  }
}

// -------------------------------------------------------------------------
__global__ __launch_bounds__(256) void loss_kernel(const float* __restrict__ acc,
                                                   float* __restrict__ out) {
  int tid = threadIdx.x;
  float v = acc[tid];
  #pragma unroll
  for (int off = 32; off > 0; off >>= 1) v += __shfl_down(v, off);
  __shared__ float part[4];
  if ((tid & 63) == 0) part[tid >> 6] = v;
  __syncthreads();
  if (tid == 0) out[0] = -(part[0] + part[1] + part[2] + part[3]) * (1.0f / NB);
}

// -------------------------------------------------------------------------
extern "C" void kernel_launch(void* const* d_in, const int* in_sizes, int n_in,
                              void* d_out, int out_size, void* d_ws, size_t ws_size,
                              hipStream_t stream) {
  const float* enc         = (const float*)d_in[0];
  const float* col_enc     = (const float*)d_in[1];
  const int*   enc_lens    = (const int*)d_in[2];
  const int*   col_lens    = (const int*)d_in[3];
  const int*   action_kind = (const int*)d_in[4];
  const int*   tgt_lens    = (const int*)d_in[5];
  const int*   prod_ids    = (const int*)d_in[6];
  const int*   col_ids     = (const int*)d_in[7];
  const int*   parent_prod = (const int*)d_in[8];
  const int*   parent_type = (const int*)d_in[9];
  const int*   parent_time = (const int*)d_in[10];
  const float* prod_embed  = (const float*)d_in[11];
  const float* type_embed  = (const float*)d_in[12];
  const float* b_lin       = (const float*)d_in[13];
  const float* W_ih        = (const float*)d_in[14];
  const float* W_hh        = (const float*)d_in[15];
  const float* b_lstm      = (const float*)d_in[16];
  const float* W_att_q     = (const float*)d_in[17];
  const float* W_att_vec   = (const float*)d_in[18];
  const float* W_r1        = (const float*)d_in[19];
  const float* b_r1        = (const float*)d_in[20];
  const float* W_r2        = (const float*)d_in[21];
  const float* b_r2        = (const float*)d_in[22];
  const float* W_col_in    = (const float*)d_in[23];
  const float* W_ptr       = (const float*)d_in[24];
  const float* w_mem       = (const float*)d_in[25];

  float* base = (float*)d_ws;
  size_t o = 0;
  float* cst    = base + o; o += 131072;
  float* appear = base + o; o += 16384;
  float* acc    = base + o; o += 256;
  int zeroN = (int)o;                                   // 147,712
  float* attq   = base + o; o += 131072;
  float* ptrq   = base + o; o += 131072;
  ushort_t* hist_u  = (ushort_t*)(base + o); o += 3932160;  // 60*256*512 bf16
  ushort_t* colin_b = (ushort_t*)(base + o); o += 1048576;
  ushort_t* ctxb    = (ushort_t*)(base + o); o += 65536;
  ushort_t* attb    = (ushort_t*)(base + o); o += 65536;
  ushort_t* r1b     = (ushort_t*)(base + o); o += 262144;
  ushort_t* WpG  = (ushort_t*)(base + o); o += 1900544;
  ushort_t* WpQ  = (ushort_t*)(base + o); o += 131072;
  ushort_t* WpV  = (ushort_t*)(base + o); o += 262144;
  ushort_t* WpRP = (ushort_t*)(base + o); o += 655360;
  ushort_t* WpCI = (ushort_t*)(base + o); o += 32768;
  ushort_t* Wr2p = (ushort_t*)(base + o); o += 114688;   // [2048][112]
  float* bias2   = base + o; o += 128;
  (void)ws_size; (void)in_sizes; (void)n_in; (void)out_size;

  zero_kernel<<<(zeroN + 255) / 256, 256, 0, stream>>>(base, zeroN);

  pack_w_perm<<<(1344 * 2048 + 255) / 256, 256, 0, stream>>>(W_ih, WpG, 1344, 0);
  pack_w_perm<<<(512 * 2048 + 255) / 256, 256, 0, stream>>>(W_hh, WpG, 512, 1344);
  pack_w<<<(512 * 512 + 255) / 256, 256, 0, stream>>>(W_att_q, WpQ, 512, 512, 512, 0, 0, 512);
  pack_w<<<(1024 * 512 + 255) / 256, 256, 0, stream>>>(W_att_vec, WpV, 1024, 512, 512, 0, 0, 512);
  pack_w<<<(512 * 2048 + 255) / 256, 256, 0, stream>>>(W_r1, WpRP, 512, 2048, 2560, 0, 0, 2048);
  pack_w<<<(512 * 512 + 255) / 256, 256, 0, stream>>>(W_ptr, WpRP, 512, 512, 2560, 0, 2048, 512);
  pack_w<<<(512 * 128 + 255) / 256, 256, 0, stream>>>(W_col_in, WpCI, 512, 128, 128, 0, 0, 128);
  r2p_kernel<<<(2049 * 98 + 255) / 256, 256, 0, stream>>>(W_r2, prod_embed, b_r2, b_lin, Wr2p, bias2);

  // colin = col_enc @ W_col_in -> bf16  (M=16384, K=512, N=128)
  gemm_bf16<<<dim3(2, 256), 256, 0, stream>>>(col_enc, 512, WpCI, colin_b, 128, 128, 512);

  for (int t = 0; t < NT; ++t) {
    ushort_t* hist_t = hist_u + (size_t)t * NBH;
    k1_gates_lstm<<<dim3(32, 4), 256, 0, stream>>>(
        action_kind, tgt_lens, prod_ids, col_ids, parent_prod, parent_type,
        parent_time, prod_embed, type_embed, b_lstm, WpG, colin_b, attb,
        hist_u, hist_t, cst, t);
    k2_attq<<<dim3(8, 4), 256, 0, stream>>>(hist_t, WpQ, attq);
    k3_attn<<<NB, 256, 0, stream>>>(enc, attq, enc_lens, ctxb);
    k4_attvec<<<dim3(8, 4), 256, 0, stream>>>(ctxb, hist_t, WpV, attb);
    k5_r1ptr<<<dim3(40, 4), 256, 0, stream>>>(attb, WpRP, b_r1, r1b, ptrq);
    k6_final<<<NB, 256, 0, stream>>>(r1b, Wr2p, bias2, attb, ptrq, col_enc,
        w_mem, col_lens, tgt_lens, action_kind, prod_ids, col_ids, appear, acc, t);
  }
  loss_kernel<<<1, 256, 0, stream>>>(acc, (float*)d_out);
}

// Round 5
// 6944.455 us; speedup vs baseline: 10.0262x; 1.1008x over previous
//
#include <hip/hip_runtime.h>
#include <math.h>

#define NB 256
#define NS 128
#define NCOL 64
#define NT 60
#define DENC 512
#define DRNN 512
#define DATT 512
#define DACT 128
#define DTYP 64
#define DG 2048
#define NEGV (-1e9f)
#define NBH 131072   // NB*DRNN (elements per hist step)

typedef unsigned short ushort_t;
typedef __attribute__((ext_vector_type(8))) short short8;
typedef __attribute__((ext_vector_type(4))) float f32x4;

__device__ __forceinline__ float sigf(float x) { return 1.0f / (1.0f + __expf(-x)); }
__device__ __forceinline__ float tanhfast(float x) {
  x = fminf(fmaxf(x, -15.0f), 15.0f);
  float e = __expf(-2.0f * x);
  return (1.0f - e) / (1.0f + e);
}
__device__ __forceinline__ ushort_t f2bf(float f) {
  union { float f; unsigned u; } v; v.f = f;
  unsigned r = v.u + 0x7fffu + ((v.u >> 16) & 1u);
  return (ushort_t)(r >> 16);
}
__device__ __forceinline__ float bf2f(ushort_t b) {
  union { unsigned u; float f; } v; v.u = ((unsigned)b) << 16; return v.f;
}
__device__ __forceinline__ void ld8(const float* p, float* d) {
  f32x4 x = *(const f32x4*)p, y = *(const f32x4*)(p + 4);
  d[0]=x[0]; d[1]=x[1]; d[2]=x[2]; d[3]=x[3];
  d[4]=y[0]; d[5]=y[1]; d[6]=y[2]; d[7]=y[3];
}
__device__ __forceinline__ short8 cvt8(const float* p) {
  f32x4 x = *(const f32x4*)p, y = *(const f32x4*)(p + 4);
  short8 r;
  r[0]=(short)f2bf(x[0]); r[1]=(short)f2bf(x[1]); r[2]=(short)f2bf(x[2]); r[3]=(short)f2bf(x[3]);
  r[4]=(short)f2bf(y[0]); r[5]=(short)f2bf(y[1]); r[6]=(short)f2bf(y[2]); r[7]=(short)f2bf(y[3]);
  return r;
}

// -------------------------------------------------------------------------
__global__ __launch_bounds__(256) void zero_kernel(float* __restrict__ p, int n) {
  int i = blockIdx.x * 256 + threadIdx.x;
  if (i < n) p[i] = 0.0f;
}

// generic f32 -> bf16 vector convert (n8 = count of 8-element groups)
__global__ __launch_bounds__(256) void cvt_bf16_kernel(const float* __restrict__ src,
    ushort_t* __restrict__ dst, int n8)
{
  int i = blockIdx.x * 256 + threadIdx.x;
  if (i < n8) *(short8*)&dst[(size_t)i * 8] = cvt8(src + (size_t)i * 8);
}

// pack f32 weight into bf16 [(K/8)][Ntot][8]
__global__ __launch_bounds__(256) void pack_w(const float* __restrict__ src,
    ushort_t* __restrict__ dst, int Ksub, int Nsub, int Ntot, int K0, int N0, int ldsrc)
{
  int idx = blockIdx.x * 256 + threadIdx.x;
  if (idx >= Ksub * Nsub) return;
  int k = idx / Nsub, n = idx - k * Nsub;
  int gk = K0 + k;
  dst[((size_t)(gk >> 3) * Ntot + (N0 + n)) * 8 + (gk & 7)] =
      f2bf(src[(size_t)k * ldsrc + n]);
}

// gate-interleaved pack for the LSTM weight: orig col n = q*512+j -> packed 4j+q
__global__ __launch_bounds__(256) void pack_w_perm(const float* __restrict__ src,
    ushort_t* __restrict__ dst, int Ksub, int K0)
{
  int idx = blockIdx.x * 256 + threadIdx.x;
  if (idx >= Ksub * DG) return;
  int k = idx / DG, n = idx - k * DG;
  int gk = K0 + k;
  int nperm = 4 * (n & 511) + (n >> 9);
  dst[((size_t)(gk >> 3) * DG + nperm) * 8 + (gk & 7)] =
      f2bf(src[(size_t)k * DG + n]);
}

// W_att_q transpose: WqT[d][k] = W[k][d], bf16
__global__ __launch_bounds__(256) void pack_wqT(const float* __restrict__ W,
    ushort_t* __restrict__ dst)
{
  int idx = blockIdx.x * 256 + threadIdx.x;
  if (idx >= 512 * 512) return;
  int k = idx >> 9, d = idx & 511;
  dst[(size_t)d * 512 + k] = f2bf(W[(size_t)k * 512 + d]);
}

// Wr2pT[j][k] = sum_d W_r2[k][d]*prod_embed[j][d]; bias2[j] = b_r2.pe[j]+b_lin[j]
__global__ __launch_bounds__(256) void r2p_kernel(const float* __restrict__ W_r2,
    const float* __restrict__ prod_embed, const float* __restrict__ b_r2,
    const float* __restrict__ b_lin, ushort_t* __restrict__ Wr2pT,
    float* __restrict__ bias2)
{
  int idx = blockIdx.x * 256 + threadIdx.x;
  if (idx >= 2049 * 98) return;
  int k = idx / 98, j = idx - k * 98;
  const float* pe = prod_embed + (size_t)j * DACT;
  if (k < 2048) {
    const float* wr = W_r2 + (size_t)k * DACT;
    float a = 0.f;
    #pragma unroll 8
    for (int d = 0; d < DACT; ++d) a = fmaf(wr[d], pe[d], a);
    Wr2pT[(size_t)j * 2048 + k] = f2bf(a);
  } else {
    float a = b_lin[j];
    #pragma unroll 8
    for (int d = 0; d < DACT; ++d) a = fmaf(b_r2[d], pe[d], a);
    bias2[j] = a;
  }
}

// standalone MFMA GEMM used once for colin (A f32)
__global__ __launch_bounds__(256) void gemm_bf16(
    const float* __restrict__ A1, int lda1,
    const ushort_t* __restrict__ Bp, ushort_t* __restrict__ Cb, int ldc,
    int N, int K)
{
  __shared__ short As[2][4096];
  __shared__ short Bs[2][4096];
  const int tid = threadIdx.x;
  const int lane = tid & 63, w = tid >> 6;
  const int wr = w >> 1, wc = w & 1;
  const int mBase = blockIdx.y * 64, nBase = blockIdx.x * 64;
  const int nt = K >> 6;
  f32x4 ra0[2], ra1[2];
  short8 rb[2];
  auto issue = [&](int kt) {
    #pragma unroll
    for (int s = 0; s < 2; ++s) {
      int slot = tid + s * 256;
      int kc = slot >> 6, m = slot & 63;
      int k0 = (kt << 6) + kc * 8;
      const float* p = A1 + (size_t)(mBase + m) * lda1 + k0;
      ra0[s] = *(const f32x4*)p;
      ra1[s] = *(const f32x4*)(p + 4);
      rb[s] = *(const short8*)(Bp + ((size_t)(k0 >> 3) * N + nBase + m) * 8);
    }
  };
  auto store = [&](int buf) {
    #pragma unroll
    for (int s = 0; s < 2; ++s) {
      int slot = tid + s * 256;
      short8 av;
      av[0]=(short)f2bf(ra0[s][0]); av[1]=(short)f2bf(ra0[s][1]);
      av[2]=(short)f2bf(ra0[s][2]); av[3]=(short)f2bf(ra0[s][3]);
      av[4]=(short)f2bf(ra1[s][0]); av[5]=(short)f2bf(ra1[s][1]);
      av[6]=(short)f2bf(ra1[s][2]); av[7]=(short)f2bf(ra1[s][3]);
      *(short8*)&As[buf][slot * 8] = av;
      *(short8*)&Bs[buf][slot * 8] = rb[s];
    }
  };
  f32x4 z4 = {0.f,0.f,0.f,0.f};
  f32x4 acc[2][2] = {{z4,z4},{z4,z4}};
  issue(0); store(0);
  __syncthreads();
  int cur = 0;
  for (int kt = 0; kt < nt; ++kt) {
    bool more = (kt + 1 < nt);
    if (more) issue(kt + 1);
    #pragma unroll
    for (int kk = 0; kk < 2; ++kk) {
      int ko = kk * 4 + (lane >> 4);
      short8 af[2], bfr[2];
      #pragma unroll
      for (int f = 0; f < 2; ++f) {
        int row = wr * 32 + f * 16 + (lane & 15);
        af[f] = *(const short8*)&As[cur][(ko * 64 + row) * 8];
        int col = wc * 32 + f * 16 + (lane & 15);
        bfr[f] = *(const short8*)&Bs[cur][(ko * 64 + col) * 8];
      }
      #pragma unroll
      for (int i = 0; i < 2; ++i)
        #pragma unroll
        for (int j = 0; j < 2; ++j)
          acc[i][j] = __builtin_amdgcn_mfma_f32_16x16x32_bf16(af[i], bfr[j], acc[i][j], 0, 0, 0);
    }
    if (more) store(cur ^ 1);
    __syncthreads();
    cur ^= 1;
  }
  #pragma unroll
  for (int i = 0; i < 2; ++i)
    #pragma unroll
    for (int j = 0; j < 2; ++j)
      #pragma unroll
      for (int r = 0; r < 4; ++r) {
        int row = mBase + wr * 32 + i * 16 + (lane >> 4) * 4 + r;
        int col = nBase + wc * 32 + j * 16 + (lane & 15);
        Cb[(size_t)row * ldc + col] = f2bf(acc[i][j][r]);
      }
}

// ---------------- core 64x64 MFMA tile engine (device side) ----------------
template <class FA, class FE>
__device__ __forceinline__ void gemm_core(char* smem, FA loadA,
    const ushort_t* Bp, int Ntot, int nBase, int ktBeg, int ktEnd, FE epi)
{
  short* As = (short*)smem;
  short* Bs = (short*)smem + 8192;
  const int tid = threadIdx.x;
  const int lane = tid & 63, w = tid >> 6;
  const int wr = w >> 1, wc = w & 1;
  f32x4 z4 = {0.f,0.f,0.f,0.f};
  f32x4 acc[2][2] = {{z4,z4},{z4,z4}};
  short8 pa[2], pb[2];
  auto issue = [&](int kt) {
    #pragma unroll
    for (int s = 0; s < 2; ++s) {
      int slot = tid + s * 256;
      int kc = slot >> 6;
      int k = (kt << 6) + (kc << 3);
      pa[s] = loadA(k);
      int n = slot & 63;
      pb[s] = *(const short8*)(Bp + ((size_t)(k >> 3) * Ntot + nBase + n) * 8);
    }
  };
  auto store = [&](int buf) {
    #pragma unroll
    for (int s = 0; s < 2; ++s) {
      int slot = tid + s * 256;
      *(short8*)&As[buf * 4096 + slot * 8] = pa[s];
      *(short8*)&Bs[buf * 4096 + slot * 8] = pb[s];
    }
  };
  issue(ktBeg); store(0);
  __syncthreads();
  int cur = 0;
  for (int kt = ktBeg; kt < ktEnd; ++kt) {
    bool more = (kt + 1 < ktEnd);
    if (more) issue(kt + 1);
    #pragma unroll
    for (int kk = 0; kk < 2; ++kk) {
      int ko = kk * 4 + (lane >> 4);
      short8 af[2], bfr[2];
      #pragma unroll
      for (int f = 0; f < 2; ++f) {
        int row = wr * 32 + f * 16 + (lane & 15);
        af[f] = *(const short8*)&As[cur * 4096 + (ko * 64 + row) * 8];
        int col = wc * 32 + f * 16 + (lane & 15);
        bfr[f] = *(const short8*)&Bs[cur * 4096 + (ko * 64 + col) * 8];
      }
      #pragma unroll
      for (int i = 0; i < 2; ++i)
        #pragma unroll
        for (int j = 0; j < 2; ++j)
          acc[i][j] = __builtin_amdgcn_mfma_f32_16x16x32_bf16(af[i], bfr[j], acc[i][j], 0, 0, 0);
    }
    if (more) store(cur ^ 1);
    __syncthreads();
    cur ^= 1;
  }
  #pragma unroll
  for (int i = 0; i < 2; ++i)
    #pragma unroll
    for (int j = 0; j < 2; ++j)
      #pragma unroll
      for (int r = 0; r < 4; ++r) {
        int rl = wr * 32 + i * 16 + (lane >> 4) * 4 + r;
        int cl = wc * 32 + j * 16 + (lane & 15);
        epi(rl, cl, acc[i][j][r]);
      }
}

// ---------------- K1: gates GEMM (fused gather) + LSTM epilogue ------------
__global__ __launch_bounds__(256) void k1_gates_lstm(
    const int* __restrict__ action_kind, const int* __restrict__ tgt_lens,
    const int* __restrict__ prod_ids, const int* __restrict__ col_ids,
    const int* __restrict__ parent_prod, const int* __restrict__ parent_type,
    const int* __restrict__ parent_time,
    const float* __restrict__ prod_embed, const float* __restrict__ type_embed,
    const float* __restrict__ b_lstm,
    const ushort_t* __restrict__ WpG, const ushort_t* __restrict__ colin_b,
    const ushort_t* __restrict__ attb, const ushort_t* __restrict__ hist_u,
    ushort_t* __restrict__ hist_t, float* __restrict__ cst, int t)
{
  __shared__ __align__(16) char smem[32768];
  const int tid = threadIdx.x;
  const int nb = blockIdx.x, mb = blockIdx.y;
  const int mBase = mb * 64, nBase = nb * 64;
  const int b = mBase + (tid & 63);
  int kp = 0, pp = 0, cp = 0, fp = 0, ft = 0, ptm = 0;
  bool pv = false;
  if (t > 0) {
    kp = action_kind[b * NT + t - 1];
    pp = prod_ids[b * NT + t - 1];
    cp = col_ids[b * NT + t - 1];
    pv = (t - 1) < tgt_lens[b];
    fp = parent_prod[b * NT + t];
    ft = parent_type[b * NT + t];
    ptm = parent_time[b * NT + t];
  }
  const ushort_t* hist_prev = hist_u + (size_t)(t - 1) * NBH;
  auto loadA = [&](int k) -> short8 {
    short8 z = {0,0,0,0,0,0,0,0};
    if (t == 0) return z;
    if (k < 128) {
      if (!pv) return z;
      if (kp == 2) return *(const short8*)(colin_b + ((size_t)(b * NCOL + cp) * DACT + k));
      int row = (kp == 1) ? 97 : pp;
      return cvt8(prod_embed + (size_t)row * DACT + k);
    } else if (k < 640) {
      return *(const short8*)(attb + (size_t)b * DATT + (k - 128));
    } else if (k < 768) {
      return cvt8(prod_embed + (size_t)fp * DACT + (k - 640));
    } else if (k < 832) {
      return cvt8(type_embed + (size_t)ft * DTYP + (k - 768));
    } else if (k < 1344) {
      return *(const short8*)(hist_u + (size_t)ptm * NBH + (size_t)b * DRNN + (k - 832));
    } else {
      return *(const short8*)(hist_prev + (size_t)b * DRNN + (k - 1344));
    }
  };
  float* sacc = (float*)smem;   // [64][69] aliases As/Bs after compute done
  auto epi = [&](int rl, int cl, float v) { sacc[rl * 69 + cl] = v; };
  gemm_core(smem, loadA, WpG, DG, nBase, 0, 29, epi);
  __syncthreads();
  {
    int r = tid & 63;
    int qrow = tid >> 6;
    #pragma unroll
    for (int q4 = 0; q4 < 4; ++q4) {
      int jloc = qrow + q4 * 4;
      int j = nb * 16 + jloc;
      float gi = sacc[r * 69 + 4 * jloc + 0] + b_lstm[j];
      float gf = sacc[r * 69 + 4 * jloc + 1] + b_lstm[512 + j];
      float gg = sacc[r * 69 + 4 * jloc + 2] + b_lstm[1024 + j];
      float go = sacc[r * 69 + 4 * jloc + 3] + b_lstm[1536 + j];
      size_t ix = (size_t)b * DRNN + j;
      float cn = sigf(gf) * cst[ix] + sigf(gi) * tanhfast(gg);
      float hn = sigf(go) * tanhfast(cn);
      cst[ix] = cn;
      hist_t[ix] = f2bf(hn);
    }
  }
}

// ---------------- K23: fused attq matvec + online-softmax attention --------
struct SmemK23 {
  float hq[DRNN];
  float sq[DENC];
  float ml[4][2];
  float cs[4][DENC];
};
__global__ __launch_bounds__(256) void k23_attq_attn(
    const ushort_t* __restrict__ hist_t, const ushort_t* __restrict__ WqT,
    const float* __restrict__ enc, const int* __restrict__ enc_lens,
    ushort_t* __restrict__ ctxb)
{
  __shared__ __align__(16) SmemK23 s;
  int b = blockIdx.x, tid = threadIdx.x;
  if (tid < 64) {
    short8 hv = *(const short8*)(hist_t + (size_t)b * DRNN + tid * 8);
    #pragma unroll
    for (int e = 0; e < 8; ++e) s.hq[tid * 8 + e] = bf2f((ushort_t)hv[e]);
  }
  __syncthreads();
  {
    int d0 = tid * 2;
    float a0 = 0.f, a1 = 0.f;
    const ushort_t* w0 = WqT + (size_t)d0 * 512;
    const ushort_t* w1 = w0 + 512;
    for (int k = 0; k < 512; k += 8) {
      short8 x0 = *(const short8*)(w0 + k);
      short8 x1 = *(const short8*)(w1 + k);
      #pragma unroll
      for (int e = 0; e < 8; ++e) {
        float hv = s.hq[k + e];
        a0 = fmaf(bf2f((ushort_t)x0[e]), hv, a0);
        a1 = fmaf(bf2f((ushort_t)x1[e]), hv, a1);
      }
    }
    s.sq[d0] = a0; s.sq[d0 + 1] = a1;
  }
  __syncthreads();
  int w = tid >> 6, lane = tid & 63;
  int el = enc_lens[b];
  float q[8];
  #pragma unroll
  for (int j = 0; j < 8; ++j) q[j] = s.sq[lane * 8 + j];
  float m = -1e30f, lr = 0.f;
  float cacc[8];
  #pragma unroll
  for (int j = 0; j < 8; ++j) cacc[j] = 0.f;
  const float* eb = enc + (size_t)b * NS * DENC + lane * 8;
  for (int sI = w; sI < el; sI += 4) {
    float ev[8];
    ld8(eb + (size_t)sI * DENC, ev);
    float d = 0.f;
    #pragma unroll
    for (int j = 0; j < 8; ++j) d = fmaf(ev[j], q[j], d);
    #pragma unroll
    for (int off = 32; off > 0; off >>= 1) d += __shfl_xor(d, off);
    float mn = fmaxf(m, d);
    float rr = __expf(m - mn), p = __expf(d - mn);
    lr = lr * rr + p;
    #pragma unroll
    for (int j = 0; j < 8; ++j) cacc[j] = cacc[j] * rr + p * ev[j];
    m = mn;
  }
  if (lane == 0) { s.ml[w][0] = m; s.ml[w][1] = lr; }
  #pragma unroll
  for (int j = 0; j < 8; ++j) s.cs[w][lane * 8 + j] = cacc[j];
  __syncthreads();
  float M = fmaxf(fmaxf(s.ml[0][0], s.ml[1][0]), fmaxf(s.ml[2][0], s.ml[3][0]));
  float f0 = __expf(s.ml[0][0] - M), f1 = __expf(s.ml[1][0] - M);
  float f2 = __expf(s.ml[2][0] - M), f3 = __expf(s.ml[3][0] - M);
  float invL = 1.f / (f0 * s.ml[0][1] + f1 * s.ml[1][1] + f2 * s.ml[2][1] + f3 * s.ml[3][1]);
  #pragma unroll
  for (int rep = 0; rep < 2; ++rep) {
    int d = tid + rep * 256;
    ctxb[(size_t)b * DENC + d] =
        f2bf((f0 * s.cs[0][d] + f1 * s.cs[1][d] + f2 * s.cs[2][d] + f3 * s.cs[3][d]) * invL);
  }
}

// ---------------- K4: att = tanh([ctx|h] @ W_att_vec) ----------------
__global__ __launch_bounds__(256) void k4_attvec(const ushort_t* __restrict__ ctxb,
    const ushort_t* __restrict__ hist_t, const ushort_t* __restrict__ WpV,
    ushort_t* __restrict__ attb)
{
  __shared__ __align__(16) char smem[32768];
  const int tid = threadIdx.x;
  const int mBase = blockIdx.y * 64, nBase = blockIdx.x * 64;
  const int b = mBase + (tid & 63);
  auto loadA = [&](int k) -> short8 {
    if (k < 512) return *(const short8*)(ctxb + (size_t)b * DENC + k);
    return *(const short8*)(hist_t + (size_t)b * DRNN + (k - 512));
  };
  auto epi = [&](int rl, int cl, float v) {
    attb[(size_t)(mBase + rl) * DATT + nBase + cl] = f2bf(tanhfast(v));
  };
  gemm_core(smem, loadA, WpV, 512, nBase, 0, 16, epi);
}

// ---------------- K5: [r1|ptr] = att @ [W_r1|W_ptr] ----------------
__global__ __launch_bounds__(256) void k5_r1ptr(const ushort_t* __restrict__ attb,
    const ushort_t* __restrict__ WpRP, const float* __restrict__ b_r1,
    ushort_t* __restrict__ r1b, float* __restrict__ ptrq)
{
  __shared__ __align__(16) char smem[32768];
  const int tid = threadIdx.x;
  const int mBase = blockIdx.y * 64, nBase = blockIdx.x * 64;
  const int b = mBase + (tid & 63);
  auto loadA = [&](int k) -> short8 {
    return *(const short8*)(attb + (size_t)b * DATT + k);
  };
  auto epi = [&](int rl, int cl, float v) {
    int col = nBase + cl, row = mBase + rl;
    if (col < 2048) r1b[(size_t)row * DG + col] = f2bf(tanhfast(v + b_r1[col]));
    else            ptrq[(size_t)row * 512 + (col - 2048)] = v;
  };
  gemm_core(smem, loadA, WpRP, 2560, nBase, 0, 8, epi);
}

// ---------------- K6: logits matvec + pointer net + loss accum -------------
__global__ __launch_bounds__(256) void k6_final(
    const ushort_t* __restrict__ r1b, const ushort_t* __restrict__ Wr2pT,
    const float* __restrict__ bias2, const ushort_t* __restrict__ attb,
    const float* __restrict__ ptrq, const ushort_t* __restrict__ colenc_b,
    const float* __restrict__ w_mem, const int* __restrict__ col_lens,
    const int* __restrict__ tgt_lens, const int* __restrict__ action_kind,
    const int* __restrict__ prod_ids, const int* __restrict__ col_ids,
    float* __restrict__ appear, float* __restrict__ acc, int t)
{
  __shared__ ushort_t sr1[2048];
  __shared__ float pq[DATT], av[DATT];
  __shared__ float lpart[2][98];
  __shared__ float logits[98];
  __shared__ float wl[NCOL];
  __shared__ float sgate;
  int b = blockIdx.x, tid = threadIdx.x;
  *(short8*)&sr1[tid * 8] = *(const short8*)(r1b + (size_t)b * DG + tid * 8);
  for (int j = tid; j < DATT; j += 256) {
    pq[j] = ptrq[(size_t)b * 512 + j];
    av[j] = bf2f(attb[(size_t)b * DATT + j]);
  }
  __syncthreads();
  // logits matvec: contiguous per-thread bf16 streams, 2 k-halves x 98 cols
  {
    int col = -1, half = 0;
    if (tid < 98) { col = tid; half = 0; }
    else if (tid >= 128 && tid < 226) { col = tid - 128; half = 1; }
    if (col >= 0) {
      int k0 = half * 1024;
      const short8* wp = (const short8*)(Wr2pT + (size_t)col * 2048 + k0);
      float a = 0.f;
      #pragma unroll 4
      for (int u = 0; u < 128; ++u) {
        short8 wv = wp[u];
        #pragma unroll
        for (int e = 0; e < 8; ++e)
          a = fmaf(bf2f((ushort_t)wv[e]), bf2f(sr1[k0 + u * 8 + e]), a);
      }
      lpart[half][col] = a;
    }
  }
  // pointer scores from bf16 col_enc
  {
    int wave = tid >> 6, lane = tid & 63;
    const ushort_t* cb = colenc_b + (size_t)b * NCOL * 512;
    for (int ci = wave; ci < NCOL; ci += 4) {
      const ushort_t* e = cb + (size_t)ci * 512;
      float a = 0.0f;
      #pragma unroll
      for (int u = 0; u < 8; ++u) {
        int d = u * 64 + lane;
        a = fmaf(bf2f(e[d]), pq[d], a);
      }
      #pragma unroll
      for (int off = 32; off > 0; off >>= 1) a += __shfl_down(a, off);
      if (lane == 0) wl[ci] = a;
    }
  }
  if (tid < 64) {
    float a = 0.0f;
    #pragma unroll
    for (int u = 0; u < 8; ++u) { int d = u * 64 + tid; a = fmaf(av[d], w_mem[d], a); }
    #pragma unroll
    for (int off = 32; off > 0; off >>= 1) a += __shfl_down(a, off);
    if (tid == 0) sgate = sigf(a);
  }
  __syncthreads();
  if (tid < 98) logits[tid] = lpart[0][tid] + lpart[1][tid] + bias2[tid];
  __syncthreads();
  if (tid < 64) {
    float m = logits[tid];
    if (tid + 64 < 98) m = fmaxf(m, logits[tid + 64]);
    #pragma unroll
    for (int off = 32; off > 0; off >>= 1) m = fmaxf(m, __shfl_down(m, off));
    m = __shfl(m, 0);
    float s = __expf(logits[tid] - m) + ((tid + 64 < 98) ? __expf(logits[tid + 64] - m) : 0.0f);
    #pragma unroll
    for (int off = 32; off > 0; off >>= 1) s += __shfl_down(s, off);
    s = __shfl(s, 0);
    float lseR = m + __logf(s);
    int clen = col_lens[b];
    float gate = sgate;
    float ap = appear[b * NCOL + tid];
    float wv = wl[tid] * (ap * gate + (1.0f - ap) * (1.0f - gate));
    wv = (tid < clen) ? wv : NEGV;
    wl[tid] = wv;
    float m2 = wv;
    #pragma unroll
    for (int off = 32; off > 0; off >>= 1) m2 = fmaxf(m2, __shfl_down(m2, off));
    m2 = __shfl(m2, 0);
    float s2 = __expf(wv - m2);
    #pragma unroll
    for (int off = 32; off > 0; off >>= 1) s2 += __shfl_down(s2, off);
    s2 = __shfl(s2, 0);
    float lse2 = m2 + __logf(s2);
    float csum = (tid < clen) ? (wv - lse2) : 0.0f;
    #pragma unroll
    for (int off = 32; off > 0; off >>= 1) csum += __shfl_down(csum, off);
    if (tid == 0) {
      int kind = action_kind[b * NT + t];
      int pid = prod_ids[b * NT + t];
      int cid = col_ids[b * NT + t];
      bool valid = (t < tgt_lens[b]);
      int gj = (kind == 1) ? 97 : pid;
      float lp_rule = logits[gj] - lseR;
      float lp_col = 0.8f * (wl[cid] - lse2) + 0.2f * csum / (float)clen;
      float lp = (kind == 2) ? lp_col : lp_rule;
      if (valid) acc[b] += lp;
      if (kind == 2 && valid)
        appear[b * NCOL + cid] = fmaxf(appear[b * NCOL + cid], 1.0f);
    }
  }
}

// -------------------------------------------------------------------------
__global__ __launch_bounds__(256) void loss_kernel(const float* __restrict__ acc,
                                                   float* __restrict__ out) {
  int tid = threadIdx.x;
  float v = acc[tid];
  #pragma unroll
  for (int off = 32; off > 0; off >>= 1) v += __shfl_down(v, off);
  __shared__ float part[4];
  if ((tid & 63) == 0) part[tid >> 6] = v;
  __syncthreads();
  if (tid == 0) out[0] = -(part[0] + part[1] + part[2] + part[3]) * (1.0f / NB);
}

// -------------------------------------------------------------------------
extern "C" void kernel_launch(void* const* d_in, const int* in_sizes, int n_in,
                              void* d_out, int out_size, void* d_ws, size_t ws_size,
                              hipStream_t stream) {
  const float* enc         = (const float*)d_in[0];
  const float* col_enc     = (const float*)d_in[1];
  const int*   enc_lens    = (const int*)d_in[2];
  const int*   col_lens    = (const int*)d_in[3];
  const int*   action_kind = (const int*)d_in[4];
  const int*   tgt_lens    = (const int*)d_in[5];
  const int*   prod_ids    = (const int*)d_in[6];
  const int*   col_ids     = (const int*)d_in[7];
  const int*   parent_prod = (const int*)d_in[8];
  const int*   parent_type = (const int*)d_in[9];
  const int*   parent_time = (const int*)d_in[10];
  const float* prod_embed  = (const float*)d_in[11];
  const float* type_embed  = (const float*)d_in[12];
  const float* b_lin       = (const float*)d_in[13];
  const float* W_ih        = (const float*)d_in[14];
  const float* W_hh        = (const float*)d_in[15];
  const float* b_lstm      = (const float*)d_in[16];
  const float* W_att_q     = (const float*)d_in[17];
  const float* W_att_vec   = (const float*)d_in[18];
  const float* W_r1        = (const float*)d_in[19];
  const float* b_r1        = (const float*)d_in[20];
  const float* W_r2        = (const float*)d_in[21];
  const float* b_r2        = (const float*)d_in[22];
  const float* W_col_in    = (const float*)d_in[23];
  const float* W_ptr       = (const float*)d_in[24];
  const float* w_mem       = (const float*)d_in[25];

  float* base = (float*)d_ws;
  size_t o = 0;
  float* cst    = base + o; o += 131072;
  float* appear = base + o; o += 16384;
  float* acc    = base + o; o += 256;
  int zeroN = (int)o;                                   // 147,712
  float* ptrq   = base + o; o += 131072;
  ushort_t* hist_u  = (ushort_t*)(base + o); o += 3932160;  // 60*256*512 bf16
  ushort_t* colin_b = (ushort_t*)(base + o); o += 1048576;
  ushort_t* ctxb    = (ushort_t*)(base + o); o += 65536;
  ushort_t* attb    = (ushort_t*)(base + o); o += 65536;
  ushort_t* r1b     = (ushort_t*)(base + o); o += 262144;
  ushort_t* WpG   = (ushort_t*)(base + o); o += 1900544;
  ushort_t* WpV   = (ushort_t*)(base + o); o += 262144;
  ushort_t* WpRP  = (ushort_t*)(base + o); o += 655360;
  ushort_t* WpCI  = (ushort_t*)(base + o); o += 32768;
  ushort_t* WqT   = (ushort_t*)(base + o); o += 131072;  // [512][512]
  ushort_t* Wr2pT = (ushort_t*)(base + o); o += 100352;  // [98][2048]
  float* bias2    = base + o; o += 128;
  ushort_t* colenc_b = (ushort_t*)(base + o); o += 4194304; // [256][64][512] bf16
  (void)ws_size; (void)in_sizes; (void)n_in; (void)out_size;

  zero_kernel<<<(zeroN + 255) / 256, 256, 0, stream>>>(base, zeroN);

  pack_w_perm<<<(1344 * 2048 + 255) / 256, 256, 0, stream>>>(W_ih, WpG, 1344, 0);
  pack_w_perm<<<(512 * 2048 + 255) / 256, 256, 0, stream>>>(W_hh, WpG, 512, 1344);
  pack_wqT<<<(512 * 512 + 255) / 256, 256, 0, stream>>>(W_att_q, WqT);
  pack_w<<<(1024 * 512 + 255) / 256, 256, 0, stream>>>(W_att_vec, WpV, 1024, 512, 512, 0, 0, 512);
  pack_w<<<(512 * 2048 + 255) / 256, 256, 0, stream>>>(W_r1, WpRP, 512, 2048, 2560, 0, 0, 2048);
  pack_w<<<(512 * 512 + 255) / 256, 256, 0, stream>>>(W_ptr, WpRP, 512, 512, 2560, 0, 2048, 512);
  pack_w<<<(512 * 128 + 255) / 256, 256, 0, stream>>>(W_col_in, WpCI, 512, 128, 128, 0, 0, 128);
  r2p_kernel<<<(2049 * 98 + 255) / 256, 256, 0, stream>>>(W_r2, prod_embed, b_r2, b_lin, Wr2pT, bias2);
  cvt_bf16_kernel<<<(1048576 + 255) / 256, 256, 0, stream>>>(col_enc, colenc_b, 1048576);

  // colin = col_enc @ W_col_in -> bf16  (M=16384, K=512, N=128)
  gemm_bf16<<<dim3(2, 256), 256, 0, stream>>>(col_enc, 512, WpCI, colin_b, 128, 128, 512);

  for (int t = 0; t < NT; ++t) {
    ushort_t* hist_t = hist_u + (size_t)t * NBH;
    k1_gates_lstm<<<dim3(32, 4), 256, 0, stream>>>(
        action_kind, tgt_lens, prod_ids, col_ids, parent_prod, parent_type,
        parent_time, prod_embed, type_embed, b_lstm, WpG, colin_b, attb,
        hist_u, hist_t, cst, t);
    k23_attq_attn<<<NB, 256, 0, stream>>>(hist_t, WqT, enc, enc_lens, ctxb);
    k4_attvec<<<dim3(8, 4), 256, 0, stream>>>(ctxb, hist_t, WpV, attb);
    k5_r1ptr<<<dim3(40, 4), 256, 0, stream>>>(attb, WpRP, b_r1, r1b, ptrq);
    k6_final<<<NB, 256, 0, stream>>>(r1b, Wr2pT, bias2, attb, ptrq, colenc_b,
        w_mem, col_lens, tgt_lens, action_kind, prod_ids, col_ids, appear, acc, t);
  }
  loss_kernel<<<1, 256, 0, stream>>>(acc, (float*)d_out);
}

// Round 7
// 3496.014 us; speedup vs baseline: 19.9160x; 1.9864x over previous
//
#include <hip/hip_runtime.h>
#include <math.h>

#define NB 256
#define NS 128
#define NCOL 64
#define NT 60
#define DENC 512
#define DRNN 512
#define DATT 512
#define DACT 128
#define DTYP 64
#define DG 2048
#define NEGV (-1e9f)
#define NBH 131072      // NB*DRNN
#define NROW 15360      // NT*NB
#define RPW 576         // ptrq_all row width (512 ptr + 64 pad, gate separate)
#define NRP 2624        // r1(2048)|ptr(512)|w_mem(1)+pad GEMM width

typedef unsigned short ushort_t;
typedef __attribute__((ext_vector_type(8))) short short8;
typedef __attribute__((ext_vector_type(4))) float f32x4;

__device__ __forceinline__ float sigf(float x) { return 1.0f / (1.0f + __expf(-x)); }
__device__ __forceinline__ float tanhfast(float x) {
  x = fminf(fmaxf(x, -15.0f), 15.0f);
  float e = __expf(-2.0f * x);
  return (1.0f - e) / (1.0f + e);
}
__device__ __forceinline__ ushort_t f2bf(float f) {
  union { float f; unsigned u; } v; v.f = f;
  unsigned r = v.u + 0x7fffu + ((v.u >> 16) & 1u);
  return (ushort_t)(r >> 16);
}
__device__ __forceinline__ float bf2f(ushort_t b) {
  union { unsigned u; float f; } v; v.u = ((unsigned)b) << 16; return v.f;
}
__device__ __forceinline__ void ld8(const float* p, float* d) {
  f32x4 x = *(const f32x4*)p, y = *(const f32x4*)(p + 4);
  d[0]=x[0]; d[1]=x[1]; d[2]=x[2]; d[3]=x[3];
  d[4]=y[0]; d[5]=y[1]; d[6]=y[2]; d[7]=y[3];
}
__device__ __forceinline__ short8 cvt8(const float* p) {
  f32x4 x = *(const f32x4*)p, y = *(const f32x4*)(p + 4);
  short8 r;
  r[0]=(short)f2bf(x[0]); r[1]=(short)f2bf(x[1]); r[2]=(short)f2bf(x[2]); r[3]=(short)f2bf(x[3]);
  r[4]=(short)f2bf(y[0]); r[5]=(short)f2bf(y[1]); r[6]=(short)f2bf(y[2]); r[7]=(short)f2bf(y[3]);
  return r;
}

// -------------------------------------------------------------------------
__global__ __launch_bounds__(256) void zero_kernel(float* __restrict__ p, int n) {
  int i = blockIdx.x * 256 + threadIdx.x;
  if (i < n) p[i] = 0.0f;
}

__global__ __launch_bounds__(256) void cvt_bf16_kernel(const float* __restrict__ src,
    ushort_t* __restrict__ dst, int n8)
{
  int i = blockIdx.x * 256 + threadIdx.x;
  if (i < n8) *(short8*)&dst[(size_t)i * 8] = cvt8(src + (size_t)i * 8);
}

// pack f32 weight into bf16 [(K/8)][Ntot][8]
__global__ __launch_bounds__(256) void pack_w(const float* __restrict__ src,
    ushort_t* __restrict__ dst, int Ksub, int Nsub, int Ntot, int K0, int N0, int ldsrc)
{
  int idx = blockIdx.x * 256 + threadIdx.x;
  if (idx >= Ksub * Nsub) return;
  int k = idx / Nsub, n = idx - k * Nsub;
  int gk = K0 + k;
  dst[((size_t)(gk >> 3) * Ntot + (N0 + n)) * 8 + (gk & 7)] =
      f2bf(src[(size_t)k * ldsrc + n]);
}

// pack W_att_q TRANSPOSED for encWq GEMM: B[d][r] = Wq[r][d]
__global__ __launch_bounds__(256) void pack_wT(const float* __restrict__ W,
    ushort_t* __restrict__ dst)
{
  int idx = blockIdx.x * 256 + threadIdx.x;
  if (idx >= 512 * 512) return;
  int r = idx >> 9, d = idx & 511;
  dst[((size_t)(d >> 3) * 512 + r) * 8 + (d & 7)] = f2bf(W[(size_t)r * 512 + d]);
}

// Wr2p packed [(2048/8)][128][8]: col j = sum_d W_r2[k][d]*prod_embed[j][d]
__global__ __launch_bounds__(256) void r2p_kernel(const float* __restrict__ W_r2,
    const float* __restrict__ prod_embed, const float* __restrict__ b_r2,
    const float* __restrict__ b_lin, ushort_t* __restrict__ Wr2p,
    float* __restrict__ bias2)
{
  int idx = blockIdx.x * 256 + threadIdx.x;
  if (idx >= 2049 * 98) return;
  int k = idx / 98, j = idx - k * 98;
  const float* pe = prod_embed + (size_t)j * DACT;
  if (k < 2048) {
    const float* wr = W_r2 + (size_t)k * DACT;
    float a = 0.f;
    #pragma unroll 8
    for (int d = 0; d < DACT; ++d) a = fmaf(wr[d], pe[d], a);
    Wr2p[((size_t)(k >> 3) * 128 + j) * 8 + (k & 7)] = f2bf(a);
  } else {
    float a = b_lin[j];
    #pragma unroll 8
    for (int d = 0; d < DACT; ++d) a = fmaf(b_r2[d], pe[d], a);
    bias2[j] = a;
  }
}

// appear_all[t][b][c] from inputs only
__global__ __launch_bounds__(64) void appear_kernel(const int* __restrict__ action_kind,
    const int* __restrict__ tgt_lens, const int* __restrict__ col_ids,
    float* __restrict__ appear_all)
{
  int b = blockIdx.x, c = threadIdx.x;
  float ap = 0.f;
  int tl = tgt_lens[b];
  for (int t = 0; t < NT; ++t) {
    appear_all[((size_t)t * NB + b) * 64 + c] = ap;
    if (t < tl && action_kind[b * NT + t] == 2 && col_ids[b * NT + t] == c) ap = 1.f;
  }
}

// standalone MFMA GEMM, A f32 (used for colin + encWq)
__global__ __launch_bounds__(256) void gemm_bf16(
    const float* __restrict__ A1, int lda1,
    const ushort_t* __restrict__ Bp, ushort_t* __restrict__ Cb, int ldc,
    int N, int K)
{
  __shared__ short As[2][4096];
  __shared__ short Bs[2][4096];
  const int tid = threadIdx.x;
  const int lane = tid & 63, w = tid >> 6;
  const int wr = w >> 1, wc = w & 1;
  const int mBase = blockIdx.y * 64, nBase = blockIdx.x * 64;
  const int nt = K >> 6;
  f32x4 ra0[2], ra1[2];
  short8 rb[2];
  auto issue = [&](int kt) {
    #pragma unroll
    for (int s = 0; s < 2; ++s) {
      int slot = tid + s * 256;
      int kc = slot >> 6, m = slot & 63;
      int k0 = (kt << 6) + kc * 8;
      const float* p = A1 + (size_t)(mBase + m) * lda1 + k0;
      ra0[s] = *(const f32x4*)p;
      ra1[s] = *(const f32x4*)(p + 4);
      rb[s] = *(const short8*)(Bp + ((size_t)(k0 >> 3) * N + nBase + m) * 8);
    }
  };
  auto store = [&](int buf) {
    #pragma unroll
    for (int s = 0; s < 2; ++s) {
      int slot = tid + s * 256;
      short8 av;
      av[0]=(short)f2bf(ra0[s][0]); av[1]=(short)f2bf(ra0[s][1]);
      av[2]=(short)f2bf(ra0[s][2]); av[3]=(short)f2bf(ra0[s][3]);
      av[4]=(short)f2bf(ra1[s][0]); av[5]=(short)f2bf(ra1[s][1]);
      av[6]=(short)f2bf(ra1[s][2]); av[7]=(short)f2bf(ra1[s][3]);
      *(short8*)&As[buf][slot * 8] = av;
      *(short8*)&Bs[buf][slot * 8] = rb[s];
    }
  };
  f32x4 z4 = {0.f,0.f,0.f,0.f};
  f32x4 acc[2][2] = {{z4,z4},{z4,z4}};
  issue(0); store(0);
  __syncthreads();
  int cur = 0;
  for (int kt = 0; kt < nt; ++kt) {
    bool more = (kt + 1 < nt);
    if (more) issue(kt + 1);
    #pragma unroll
    for (int kk = 0; kk < 2; ++kk) {
      int ko = kk * 4 + (lane >> 4);
      short8 af[2], bfr[2];
      #pragma unroll
      for (int f = 0; f < 2; ++f) {
        int row = wr * 32 + f * 16 + (lane & 15);
        af[f] = *(const short8*)&As[cur][(ko * 64 + row) * 8];
        int col = wc * 32 + f * 16 + (lane & 15);
        bfr[f] = *(const short8*)&Bs[cur][(ko * 64 + col) * 8];
      }
      #pragma unroll
      for (int i = 0; i < 2; ++i)
        #pragma unroll
        for (int j = 0; j < 2; ++j)
          acc[i][j] = __builtin_amdgcn_mfma_f32_16x16x32_bf16(af[i], bfr[j], acc[i][j], 0, 0, 0);
    }
    if (more) store(cur ^ 1);
    __syncthreads();
    cur ^= 1;
  }
  #pragma unroll
  for (int i = 0; i < 2; ++i)
    #pragma unroll
    for (int j = 0; j < 2; ++j)
      #pragma unroll
      for (int r = 0; r < 4; ++r) {
        int row = mBase + wr * 32 + i * 16 + (lane >> 4) * 4 + r;
        int col = nBase + wc * 32 + j * 16 + (lane & 15);
        Cb[(size_t)row * ldc + col] = f2bf(acc[i][j][r]);
      }
}

// ---------------- core 64x64 MFMA tile engine (loadA + loadB lambdas) ------
template <class FA, class FB, class FE>
__device__ __forceinline__ void gemm_core(char* smem, FA loadA, FB loadB,
    int ktBeg, int ktEnd, FE epi)
{
  short* As = (short*)smem;
  short* Bs = (short*)smem + 8192;
  const int tid = threadIdx.x;
  const int lane = tid & 63, w = tid >> 6;
  const int wr = w >> 1, wc = w & 1;
  f32x4 z4 = {0.f,0.f,0.f,0.f};
  f32x4 acc[2][2] = {{z4,z4},{z4,z4}};
  short8 pa[2], pb[2];
  auto issue = [&](int kt) {
    #pragma unroll
    for (int s = 0; s < 2; ++s) {
      int slot = tid + s * 256;
      int kc = slot >> 6;
      int k = (kt << 6) + (kc << 3);
      pa[s] = loadA(k);
      pb[s] = loadB(slot & 63, k);
    }
  };
  auto store = [&](int buf) {
    #pragma unroll
    for (int s = 0; s < 2; ++s) {
      int slot = tid + s * 256;
      *(short8*)&As[buf * 4096 + slot * 8] = pa[s];
      *(short8*)&Bs[buf * 4096 + slot * 8] = pb[s];
    }
  };
  issue(ktBeg); store(0);
  __syncthreads();
  int cur = 0;
  for (int kt = ktBeg; kt < ktEnd; ++kt) {
    bool more = (kt + 1 < ktEnd);
    if (more) issue(kt + 1);
    #pragma unroll
    for (int kk = 0; kk < 2; ++kk) {
      int ko = kk * 4 + (lane >> 4);
      short8 af[2], bfr[2];
      #pragma unroll
      for (int f = 0; f < 2; ++f) {
        int row = wr * 32 + f * 16 + (lane & 15);
        af[f] = *(const short8*)&As[cur * 4096 + (ko * 64 + row) * 8];
        int col = wc * 32 + f * 16 + (lane & 15);
        bfr[f] = *(const short8*)&Bs[cur * 4096 + (ko * 64 + col) * 8];
      }
      #pragma unroll
      for (int i = 0; i < 2; ++i)
        #pragma unroll
        for (int j = 0; j < 2; ++j)
          acc[i][j] = __builtin_amdgcn_mfma_f32_16x16x32_bf16(af[i], bfr[j], acc[i][j], 0, 0, 0);
    }
    if (more) store(cur ^ 1);
    __syncthreads();
    cur ^= 1;
  }
  #pragma unroll
  for (int i = 0; i < 2; ++i)
    #pragma unroll
    for (int j = 0; j < 2; ++j)
      #pragma unroll
      for (int r = 0; r < 4; ++r) {
        int rl = wr * 32 + i * 16 + (lane >> 4) * 4 + r;
        int cl = wc * 32 + j * 16 + (lane & 15);
        epi(rl, cl, acc[i][j][r]);
      }
}

// ---------------- K1: gates GEMM, split-K x2, fused gather -----------------
__global__ __launch_bounds__(256) void k1_gates(
    const int* __restrict__ action_kind, const int* __restrict__ tgt_lens,
    const int* __restrict__ prod_ids, const int* __restrict__ col_ids,
    const int* __restrict__ parent_prod, const int* __restrict__ parent_type,
    const int* __restrict__ parent_time,
    const float* __restrict__ prod_embed, const float* __restrict__ type_embed,
    const ushort_t* __restrict__ WpG, const ushort_t* __restrict__ colin_b,
    const ushort_t* __restrict__ att_all, const ushort_t* __restrict__ hist_u,
    float* __restrict__ gates0, float* __restrict__ gates1, int t)
{
  __shared__ __align__(16) char smem[32768];
  const int tid = threadIdx.x;
  const int nb = blockIdx.x, mb = blockIdx.y, ks = blockIdx.z;
  const int mBase = mb * 64, nBase = nb * 64;
  const int b = mBase + (tid & 63);
  int kp = action_kind[b * NT + t - 1];
  int pp = prod_ids[b * NT + t - 1];
  int cp = col_ids[b * NT + t - 1];
  bool pv = (t - 1) < tgt_lens[b];
  int fp = parent_prod[b * NT + t];
  int ft = parent_type[b * NT + t];
  int ptm = parent_time[b * NT + t];
  const ushort_t* hist_prev = hist_u + (size_t)(t - 1) * NBH;
  const ushort_t* att_prev = att_all + (size_t)(t - 1) * NB * DATT;
  auto loadA = [&](int k) -> short8 {
    short8 z = {0,0,0,0,0,0,0,0};
    if (k < 128) {
      if (!pv) return z;
      if (kp == 2) return *(const short8*)(colin_b + ((size_t)(b * NCOL + cp) * DACT + k));
      int row = (kp == 1) ? 97 : pp;
      return cvt8(prod_embed + (size_t)row * DACT + k);
    } else if (k < 640) {
      return *(const short8*)(att_prev + (size_t)b * DATT + (k - 128));
    } else if (k < 768) {
      return cvt8(prod_embed + (size_t)fp * DACT + (k - 640));
    } else if (k < 832) {
      return cvt8(type_embed + (size_t)ft * DTYP + (k - 768));
    } else if (k < 1344) {
      return *(const short8*)(hist_u + (size_t)ptm * NBH + (size_t)b * DRNN + (k - 832));
    } else {
      return *(const short8*)(hist_prev + (size_t)b * DRNN + (k - 1344));
    }
  };
  auto loadB = [&](int n, int k) -> short8 {
    return *(const short8*)(WpG + ((size_t)(k >> 3) * DG + nBase + n) * 8);
  };
  float* gp = ks ? gates1 : gates0;
  auto epi = [&](int rl, int cl, float v) {
    gp[(size_t)(mBase + rl) * DG + nBase + cl] = v;
  };
  gemm_core(smem, loadA, loadB, ks ? 15 : 0, ks ? 29 : 15, epi);
}

// ---------------- K23: LSTM + online-softmax attention (scores via encWq) --
struct SmemK23 { float hq[DRNN]; float ml[4][2]; float cs[4][DENC]; };
__global__ __launch_bounds__(256) void k23_lstm_attn(
    const float* __restrict__ g0, const float* __restrict__ g1,
    const float* __restrict__ b_lstm, float* __restrict__ cst,
    ushort_t* __restrict__ hist_t,
    const ushort_t* __restrict__ encWq, const float* __restrict__ enc,
    const int* __restrict__ enc_lens, ushort_t* __restrict__ ctxb)
{
  __shared__ __align__(16) SmemK23 s;
  int b = blockIdx.x, tid = threadIdx.x;
  #pragma unroll
  for (int r = 0; r < 2; ++r) {
    int j = tid + r * 256;
    const float* p0 = g0 + (size_t)b * DG;
    const float* p1 = g1 + (size_t)b * DG;
    float gi = p0[j]        + p1[j]        + b_lstm[j];
    float gf = p0[512 + j]  + p1[512 + j]  + b_lstm[512 + j];
    float gg = p0[1024 + j] + p1[1024 + j] + b_lstm[1024 + j];
    float go = p0[1536 + j] + p1[1536 + j] + b_lstm[1536 + j];
    size_t ix = (size_t)b * DRNN + j;
    float cn = sigf(gf) * cst[ix] + sigf(gi) * tanhfast(gg);
    float hn = sigf(go) * tanhfast(cn);
    cst[ix] = cn;
    hist_t[ix] = f2bf(hn);
    s.hq[j] = hn;
  }
  __syncthreads();
  int w = tid >> 6, lane = tid & 63;
  int el = enc_lens[b];
  float q[8];
  #pragma unroll
  for (int j = 0; j < 8; ++j) q[j] = s.hq[lane * 8 + j];
  float m = -1e30f, lr = 0.f;
  float cacc[8];
  #pragma unroll
  for (int j = 0; j < 8; ++j) cacc[j] = 0.f;
  const ushort_t* eWb = encWq + (size_t)b * NS * DENC + lane * 8;
  const float* eb = enc + (size_t)b * NS * DENC + lane * 8;
  for (int sI = w; sI < el; sI += 4) {
    short8 xr = *(const short8*)(eWb + (size_t)sI * DENC);
    float ev[8];
    ld8(eb + (size_t)sI * DENC, ev);
    float d = 0.f;
    #pragma unroll
    for (int j = 0; j < 8; ++j) d = fmaf(bf2f((ushort_t)xr[j]), q[j], d);
    #pragma unroll
    for (int off = 32; off > 0; off >>= 1) d += __shfl_xor(d, off);
    float mn = fmaxf(m, d);
    float rr = __expf(m - mn), p = __expf(d - mn);
    lr = lr * rr + p;
    #pragma unroll
    for (int j = 0; j < 8; ++j) cacc[j] = cacc[j] * rr + p * ev[j];
    m = mn;
  }
  if (lane == 0) { s.ml[w][0] = m; s.ml[w][1] = lr; }
  #pragma unroll
  for (int j = 0; j < 8; ++j) s.cs[w][lane * 8 + j] = cacc[j];
  __syncthreads();
  float M = fmaxf(fmaxf(s.ml[0][0], s.ml[1][0]), fmaxf(s.ml[2][0], s.ml[3][0]));
  float f0 = __expf(s.ml[0][0] - M), f1 = __expf(s.ml[1][0] - M);
  float f2 = __expf(s.ml[2][0] - M), f3 = __expf(s.ml[3][0] - M);
  float invL = 1.f / (f0 * s.ml[0][1] + f1 * s.ml[1][1] + f2 * s.ml[2][1] + f3 * s.ml[3][1]);
  #pragma unroll
  for (int rep = 0; rep < 2; ++rep) {
    int d = tid + rep * 256;
    ctxb[(size_t)b * DENC + d] =
        f2bf((f0 * s.cs[0][d] + f1 * s.cs[1][d] + f2 * s.cs[2][d] + f3 * s.cs[3][d]) * invL);
  }
}

// ---------------- K4: att_all[t] = tanh([ctx|h] @ W_att_vec) ---------------
__global__ __launch_bounds__(256) void k4_attvec(const ushort_t* __restrict__ ctxb,
    const ushort_t* __restrict__ hist_t, const ushort_t* __restrict__ WpV,
    ushort_t* __restrict__ att_all, int t)
{
  __shared__ __align__(16) char smem[32768];
  const int tid = threadIdx.x;
  const int mBase = blockIdx.y * 64, nBase = blockIdx.x * 64;
  const int b = mBase + (tid & 63);
  auto loadA = [&](int k) -> short8 {
    if (k < 512) return *(const short8*)(ctxb + (size_t)b * DENC + k);
    return *(const short8*)(hist_t + (size_t)b * DRNN + (k - 512));
  };
  auto loadB = [&](int n, int k) -> short8 {
    return *(const short8*)(WpV + ((size_t)(k >> 3) * 512 + nBase + n) * 8);
  };
  auto epi = [&](int rl, int cl, float v) {
    att_all[((size_t)t * NB + mBase + rl) * DATT + nBase + cl] = f2bf(tanhfast(v));
  };
  gemm_core(smem, loadA, loadB, 0, 16, epi);
}

// ---------------- tail: big r1|ptr|gate GEMM (chunk of 15 steps) -----------
__global__ __launch_bounds__(256) void kbig_r1ptr(const ushort_t* __restrict__ att_all,
    const ushort_t* __restrict__ WpRP, const float* __restrict__ b_r1,
    ushort_t* __restrict__ r1c, ushort_t* __restrict__ ptrq_all,
    float* __restrict__ gate_all, int rowBase)
{
  __shared__ __align__(16) char smem[32768];
  const int tid = threadIdx.x;
  const int mBase = blockIdx.y * 64, nBase = blockIdx.x * 64;
  const size_t grow = (size_t)rowBase + mBase + (tid & 63);
  auto loadA = [&](int k) -> short8 {
    return *(const short8*)(att_all + grow * DATT + k);
  };
  auto loadB = [&](int n, int k) -> short8 {
    return *(const short8*)(WpRP + ((size_t)(k >> 3) * NRP + nBase + n) * 8);
  };
  auto epi = [&](int rl, int cl, float v) {
    int col = nBase + cl;
    size_t gr = (size_t)rowBase + mBase + rl;
    if (col < 2048)      r1c[(size_t)(mBase + rl) * DG + col] = f2bf(tanhfast(v + b_r1[col]));
    else if (col < 2560) ptrq_all[gr * RPW + (col - 2048)] = f2bf(v);
    else if (col == 2560) gate_all[gr] = v;
  };
  gemm_core(smem, loadA, loadB, 0, 8, epi);
}

// ---------------- tail: logits GEMM (chunk) --------------------------------
__global__ __launch_bounds__(256) void klogits(const ushort_t* __restrict__ r1c,
    const ushort_t* __restrict__ Wr2p, float* __restrict__ logits_all, int rowBase)
{
  __shared__ __align__(16) char smem[32768];
  const int tid = threadIdx.x;
  const int mBase = blockIdx.y * 64, nBase = blockIdx.x * 64;
  auto loadA = [&](int k) -> short8 {
    return *(const short8*)(r1c + (size_t)(mBase + (tid & 63)) * DG + k);
  };
  auto loadB = [&](int n, int k) -> short8 {
    return *(const short8*)(Wr2p + ((size_t)(k >> 3) * 128 + nBase + n) * 8);
  };
  auto epi = [&](int rl, int cl, float v) {
    logits_all[((size_t)rowBase + mBase + rl) * 128 + nBase + cl] = v;
  };
  gemm_core(smem, loadA, loadB, 0, 32, epi);
}

// ---------------- tail: w_c[t][b][c] = ptrq[t,b,:].col_enc[b,c,:] ----------
__global__ __launch_bounds__(256) void kwc(const ushort_t* __restrict__ ptrq_all,
    const ushort_t* __restrict__ colenc_b, float* __restrict__ w_c_all)
{
  __shared__ __align__(16) char smem[32768];
  const int tid = threadIdx.x;
  const int b = blockIdx.x;
  const int tt = tid & 63;
  auto loadA = [&](int k) -> short8 {
    short8 z = {0,0,0,0,0,0,0,0};
    if (tt >= NT) return z;
    return *(const short8*)(ptrq_all + ((size_t)tt * NB + b) * RPW + k);
  };
  auto loadB = [&](int n, int k) -> short8 {
    return *(const short8*)(colenc_b + ((size_t)b * NCOL + n) * 512 + k);
  };
  auto epi = [&](int rl, int cl, float v) {
    if (rl < NT) w_c_all[((size_t)rl * NB + b) * 64 + cl] = v;
  };
  gemm_core(smem, loadA, loadB, 0, 8, epi);
}

// ---------------- tail: per-(t,b) softmaxes + loss -------------------------
__global__ __launch_bounds__(64) void kfinal(
    const float* __restrict__ logits_all, const float* __restrict__ bias2,
    const float* __restrict__ w_c_all, const float* __restrict__ gate_all,
    const float* __restrict__ appear_all, const int* __restrict__ col_lens,
    const int* __restrict__ tgt_lens, const int* __restrict__ action_kind,
    const int* __restrict__ prod_ids, const int* __restrict__ col_ids,
    float* __restrict__ loss_tb)
{
  int row = blockIdx.x;
  int t = row >> 8, b = row & 255;
  int c = threadIdx.x;
  float l0 = logits_all[(size_t)row * 128 + c] + bias2[c];
  float l1 = (c + 64 < 98) ? logits_all[(size_t)row * 128 + 64 + c] + bias2[64 + c] : -1e30f;
  float m = fmaxf(l0, l1);
  #pragma unroll
  for (int off = 32; off > 0; off >>= 1) m = fmaxf(m, __shfl_down(m, off));
  m = __shfl(m, 0);
  float sv = __expf(l0 - m) + ((c + 64 < 98) ? __expf(l1 - m) : 0.f);
  #pragma unroll
  for (int off = 32; off > 0; off >>= 1) sv += __shfl_down(sv, off);
  sv = __shfl(sv, 0);
  float lseR = m + __logf(sv);
  int clen = col_lens[b];
  float gate = sigf(gate_all[row]);
  float ap = appear_all[(size_t)row * 64 + c];
  float wc = w_c_all[(size_t)row * 64 + c];
  float wv = wc * (ap * gate + (1.f - ap) * (1.f - gate));
  wv = (c < clen) ? wv : NEGV;
  float m2 = wv;
  #pragma unroll
  for (int off = 32; off > 0; off >>= 1) m2 = fmaxf(m2, __shfl_down(m2, off));
  m2 = __shfl(m2, 0);
  float s2 = __expf(wv - m2);
  #pragma unroll
  for (int off = 32; off > 0; off >>= 1) s2 += __shfl_down(s2, off);
  s2 = __shfl(s2, 0);
  float lse2 = m2 + __logf(s2);
  float csum = (c < clen) ? (wv - lse2) : 0.f;
  #pragma unroll
  for (int off = 32; off > 0; off >>= 1) csum += __shfl_down(csum, off);
  int kind = action_kind[b * NT + t];
  int cid = col_ids[b * NT + t];
  float wcid = __shfl(wv, cid);
  if (c == 0) {
    int pid = prod_ids[b * NT + t];
    bool valid = t < tgt_lens[b];
    int gj = (kind == 1) ? 97 : pid;
    float lgj = logits_all[(size_t)row * 128 + gj] + bias2[gj];
    float lp_rule = lgj - lseR;
    float lp_col = 0.8f * (wcid - lse2) + 0.2f * csum / (float)clen;
    float lp = (kind == 2) ? lp_col : lp_rule;
    loss_tb[row] = valid ? lp : 0.f;
  }
}

// -------------------------------------------------------------------------
__global__ __launch_bounds__(256) void loss_reduce(const float* __restrict__ loss_tb,
                                                   float* __restrict__ out) {
  int tid = threadIdx.x;
  float v = 0.f;
  for (int k = 0; k < NT; ++k) v += loss_tb[(size_t)k * NB + tid];
  #pragma unroll
  for (int off = 32; off > 0; off >>= 1) v += __shfl_down(v, off);
  __shared__ float part[4];
  if ((tid & 63) == 0) part[tid >> 6] = v;
  __syncthreads();
  if (tid == 0) out[0] = -(part[0] + part[1] + part[2] + part[3]) * (1.0f / NB);
}

// -------------------------------------------------------------------------
extern "C" void kernel_launch(void* const* d_in, const int* in_sizes, int n_in,
                              void* d_out, int out_size, void* d_ws, size_t ws_size,
                              hipStream_t stream) {
  const float* enc         = (const float*)d_in[0];
  const float* col_enc     = (const float*)d_in[1];
  const int*   enc_lens    = (const int*)d_in[2];
  const int*   col_lens    = (const int*)d_in[3];
  const int*   action_kind = (const int*)d_in[4];
  const int*   tgt_lens    = (const int*)d_in[5];
  const int*   prod_ids    = (const int*)d_in[6];
  const int*   col_ids     = (const int*)d_in[7];
  const int*   parent_prod = (const int*)d_in[8];
  const int*   parent_type = (const int*)d_in[9];
  const int*   parent_time = (const int*)d_in[10];
  const float* prod_embed  = (const float*)d_in[11];
  const float* type_embed  = (const float*)d_in[12];
  const float* b_lin       = (const float*)d_in[13];
  const float* W_ih        = (const float*)d_in[14];
  const float* W_hh        = (const float*)d_in[15];
  const float* b_lstm      = (const float*)d_in[16];
  const float* W_att_q     = (const float*)d_in[17];
  const float* W_att_vec   = (const float*)d_in[18];
  const float* W_r1        = (const float*)d_in[19];
  const float* b_r1        = (const float*)d_in[20];
  const float* W_r2        = (const float*)d_in[21];
  const float* b_r2        = (const float*)d_in[22];
  const float* W_col_in    = (const float*)d_in[23];
  const float* W_ptr       = (const float*)d_in[24];
  const float* w_mem       = (const float*)d_in[25];

  float* base = (float*)d_ws;
  size_t o = 0;
  float* cst    = base + o; o += 131072;
  float* gates0 = base + o; o += 524288;
  float* gates1 = base + o; o += 524288;
  int zeroN = (int)o;                                   // 1,179,648
  ushort_t* hist_u = (ushort_t*)(base + o); o += 3932160;   // loop; tail alias: logits_all
  float* logits_all = (float*)hist_u;                       // [15360][128] f32 (tail)
  ushort_t* colin_b = (ushort_t*)(base + o); o += 1048576;
  ushort_t* ctxb    = (ushort_t*)(base + o); o += 65536;
  float* encWq_f    = base + o; o += 8388608;               // loop: encWq bf16 [32768][512]
  ushort_t* encWq   = (ushort_t*)encWq_f;
  ushort_t* colenc_b = (ushort_t*)encWq_f;                  // tail alias (4,194,304 f32u)
  ushort_t* r1c      = (ushort_t*)(encWq_f + 4194304);      // tail alias [3840][2048] bf16
  ushort_t* att_all  = (ushort_t*)(base + o); o += 3932160; // [15360][512] bf16
  ushort_t* ptrq_all = (ushort_t*)(base + o); o += 4423680; // [15360][576] bf16
  float* gate_all    = base + o; o += 15360;
  float* w_c_all     = base + o; o += 983040;
  float* appear_all  = base + o; o += 983040;
  float* loss_tb     = base + o; o += 15360;
  ushort_t* WpG   = (ushort_t*)(base + o); o += 1900544;
  ushort_t* WqTp  = (ushort_t*)(base + o); o += 131072;
  ushort_t* WpV   = (ushort_t*)(base + o); o += 262144;
  ushort_t* WpRP  = (ushort_t*)(base + o); o += 671744;     // [(512/8)][2624][8]
  ushort_t* WpCI  = (ushort_t*)(base + o); o += 32768;
  ushort_t* Wr2p  = (ushort_t*)(base + o); o += 131072;     // [(2048/8)][128][8]
  float* bias2    = base + o; o += 128;
  (void)ws_size; (void)in_sizes; (void)n_in; (void)out_size;

  zero_kernel<<<(zeroN + 255) / 256, 256, 0, stream>>>(base, zeroN);
  zero_kernel<<<(671744 + 255) / 256, 256, 0, stream>>>((float*)WpRP, 671744);
  zero_kernel<<<(131072 + 255) / 256, 256, 0, stream>>>((float*)Wr2p, 131072);

  pack_w<<<(1344 * 2048 + 255) / 256, 256, 0, stream>>>(W_ih, WpG, 1344, 2048, 2048, 0, 0, 2048);
  pack_w<<<(512 * 2048 + 255) / 256, 256, 0, stream>>>(W_hh, WpG, 512, 2048, 2048, 1344, 0, 2048);
  pack_wT<<<(512 * 512 + 255) / 256, 256, 0, stream>>>(W_att_q, WqTp);
  pack_w<<<(1024 * 512 + 255) / 256, 256, 0, stream>>>(W_att_vec, WpV, 1024, 512, 512, 0, 0, 512);
  pack_w<<<(512 * 2048 + 255) / 256, 256, 0, stream>>>(W_r1, WpRP, 512, 2048, NRP, 0, 0, 2048);
  pack_w<<<(512 * 512 + 255) / 256, 256, 0, stream>>>(W_ptr, WpRP, 512, 512, NRP, 0, 2048, 512);
  pack_w<<<(512 + 255) / 256, 256, 0, stream>>>(w_mem, WpRP, 512, 1, NRP, 0, 2560, 1);
  pack_w<<<(512 * 128 + 255) / 256, 256, 0, stream>>>(W_col_in, WpCI, 512, 128, 128, 0, 0, 128);
  r2p_kernel<<<(2049 * 98 + 255) / 256, 256, 0, stream>>>(W_r2, prod_embed, b_r2, b_lin, Wr2p, bias2);
  appear_kernel<<<NB, 64, 0, stream>>>(action_kind, tgt_lens, col_ids, appear_all);

  // colin = col_enc @ W_col_in (bf16 out), encWq = enc @ Wq^T (bf16 out)
  gemm_bf16<<<dim3(2, 256), 256, 0, stream>>>(col_enc, 512, WpCI, colin_b, 128, 128, 512);
  gemm_bf16<<<dim3(8, 512), 256, 0, stream>>>(enc, 512, WqTp, encWq, 512, 512, 512);

  // ---- recurrent loop: 3 nodes/step ----
  for (int t = 0; t < NT; ++t) {
    ushort_t* hist_t = hist_u + (size_t)t * NBH;
    if (t > 0)
      k1_gates<<<dim3(32, 4, 2), 256, 0, stream>>>(
          action_kind, tgt_lens, prod_ids, col_ids, parent_prod, parent_type,
          parent_time, prod_embed, type_embed, WpG, colin_b, att_all, hist_u,
          gates0, gates1, t);
    k23_lstm_attn<<<NB, 256, 0, stream>>>(gates0, gates1, b_lstm, cst, hist_t,
                                          encWq, enc, enc_lens, ctxb);
    k4_attvec<<<dim3(8, 4), 256, 0, stream>>>(ctxb, hist_t, WpV, att_all, t);
  }

  // ---- batched tail ----
  cvt_bf16_kernel<<<(1048576 + 255) / 256, 256, 0, stream>>>(col_enc, colenc_b, 1048576);
  for (int ch = 0; ch < 4; ++ch) {
    int rowBase = ch * 3840;
    kbig_r1ptr<<<dim3(41, 60), 256, 0, stream>>>(att_all, WpRP, b_r1, r1c,
                                                 ptrq_all, gate_all, rowBase);
    klogits<<<dim3(2, 60), 256, 0, stream>>>(r1c, Wr2p, logits_all, rowBase);
  }
  kwc<<<NB, 256, 0, stream>>>(ptrq_all, colenc_b, w_c_all);
  kfinal<<<NROW, 64, 0, stream>>>(logits_all, bias2, w_c_all, gate_all,
      appear_all, col_lens, tgt_lens, action_kind, prod_ids, col_ids, loss_tb);
  loss_reduce<<<1, 256, 0, stream>>>(loss_tb, (float*)d_out);
}